// Round 4
// baseline (227.312 us; speedup 1.0000x reference)
//
#include <hip/hip_runtime.h>
#include <hip/hip_bf16.h>
#include <math.h>

#define B_    8
#define R_    64
#define C_    16
#define D_    128
#define NPAIR 2016
#define CD    2048
#define PG    16
#define NPG   126
#define XSTR  136
#define LSTR  68
#define NEG_BIG (-1e30f)
#define SCALE 0.022097086912079608f   // 1/sqrt(2048)

typedef __attribute__((ext_vector_type(8))) short short8;
typedef __attribute__((ext_vector_type(4))) float float4v;

// ---- ws layout (ushort offsets) ----
#define WMH  0u         // P split-hi, layout [d][e]
#define WML  16384u
#define WSH  98304u     // s1W^T plain bf16 [n][k]
#define VECO 131072u    // fp32[257]: mb[0..128), kq[128..256), s0[256]
#define QBKO 131592u    // fp32[512]
#define MO   132616u    // bf16 M[b][r][2048]
#define XTO  1181192u   // bf16 XT[b][cd][64]
#define GTO  2229768u   // bf16 GT[b][cd][64]
#define HO   3278344u   // bf16 H[b][r][2048]

// fast RNE bf16 (inputs finite by construction — no NaN path)
__device__ __forceinline__ unsigned short f2b(float f){
    union { float f; unsigned int u; } v; v.f = f;
    const unsigned int r = v.u + 0x7FFFu + ((v.u >> 16) & 1u);
    return (unsigned short)(r >> 16);
}
__device__ __forceinline__ float b2f(unsigned short u){
    union { unsigned int i; float f; } v; v.i = ((unsigned int)u) << 16; return v.f;
}
__device__ __forceinline__ float lo2f(unsigned int u){
    union { unsigned int i; float f; } v; v.i = u << 16; return v.f;
}
__device__ __forceinline__ float hif2f(unsigned int u){
    union { unsigned int i; float f; } v; v.i = u & 0xffff0000u; return v.f;
}
// single-instruction packed bf16 convert (RNE, same rounding as f2b)
__device__ __forceinline__ unsigned int pack2(float a, float b){
    unsigned int r;
    asm("v_cvt_pk_bf16_f32 %0, %1, %2" : "=v"(r) : "v"(a), "v"(b));
    return r;
}
__device__ __forceinline__ unsigned short f2b1(float a){
    unsigned int r;
    asm("v_cvt_pk_bf16_f32 %0, %1, %1" : "=v"(r) : "v"(a));
    return (unsigned short)r;
}
__device__ __forceinline__ void split_bf(float v, float* hi, float* lo){
    union { float f; unsigned int u; } x; x.f = v;
    const unsigned int r = (x.u + 0x7FFFu + ((x.u >> 16) & 1u)) & 0xffff0000u;
    union { unsigned int u; float f; } h; h.u = r;
    *hi = h.f; *lo = v - h.f;
}
// split to bf16 pair directly (bit-identical to split_bf + f2b on both halves)
__device__ __forceinline__ void splitw(float v, short* h, short* l){
    union { float f; unsigned int u; } x; x.f = v;
    const unsigned int rh = (x.u + 0x7FFFu + ((x.u >> 16) & 1u)) & 0xffff0000u;
    union { unsigned int u; float f; } hf; hf.u = rh;
    *h = (short)(rh >> 16);
    *l = (short)f2b(v - hf.f);
}
// no clamp needed: exp(+inf)->inf, rcp(inf)->0 ; exp(-inf)->0 -> 1. Inputs finite.
__device__ __forceinline__ float sigmoid_safe(float x){
    return __builtin_amdgcn_rcpf(1.f + __expf(-x));
}
// tanh-GELU via sigmoid identity (empirically error-neutral here, R12/R13 data)
__device__ __forceinline__ float gelu_tanh(float x){
    const float u = x*x;
    const float g2 = x*(1.5957691216057308f + 0.07135481627159f*u);
    return x * sigmoid_safe(g2);
}

// ===== launch A (small): P split + vectors only (65 blocks) =====
__global__ __launch_bounds__(256) void k_prepA(
    const float* __restrict__ qW, const float* __restrict__ qb,
    const float* __restrict__ kW, const float* __restrict__ kb,
    unsigned short* __restrict__ ws)
{
    const int bid = blockIdx.x, t = threadIdx.x;
    if (bid < 64){
        __shared__ float sKW[2][128];
        const int e0 = bid*2;
        sKW[t>>7][t&127] = kW[(e0 + (t>>7))*128 + (t&127)];
        __syncthreads();
        const int e = t>>7, d = t&127;
        const float* qr = qW + d*128;
        const float* kr = sKW[e];
        float acc = 0.f;
        #pragma unroll 8
        for (int g = 0; g < 128; g += 4){
            const float4 qv = *reinterpret_cast<const float4*>(qr + g);
            acc += qv.x*kr[g] + qv.y*kr[g+1] + qv.z*kr[g+2] + qv.w*kr[g+3];
        }
        float hi, lo; split_bf(acc, &hi, &lo);
        ws[WMH + d*128 + (e0+e)] = f2b(hi);
        ws[WML + d*128 + (e0+e)] = f2b(lo);
    } else {
        float* vec = (float*)(ws + VECO);
        if (t < 128){
            float a1 = 0.f, a2 = 0.f;
            #pragma unroll 8
            for (int g = 0; g < 128; g += 4){
                const float4 q4 = *reinterpret_cast<const float4*>(qW + t*128 + g);
                const float4 k4 = *reinterpret_cast<const float4*>(kW + t*128 + g);
                const float4 kb4 = *reinterpret_cast<const float4*>(kb + g);
                const float4 qb4 = *reinterpret_cast<const float4*>(qb + g);
                a1 += q4.x*kb4.x + q4.y*kb4.y + q4.z*kb4.z + q4.w*kb4.w;
                a2 += k4.x*qb4.x + k4.y*qb4.y + k4.z*qb4.z + k4.w*qb4.w;
            }
            vec[t] = a1;        // mb[d]
            vec[128 + t] = a2;  // kq[e]
        } else if (t == 128){
            float a = 0.f;
            for (int g = 0; g < 128; ++g) a = fmaf(qb[g], kb[g], a);
            vec[256] = a;       // s0
        }
    }
}

// ===== launch B: [0,128) H | [128,256) M+qbk | [256,384) GT | [384,388) s1W | [388,516) XT =====
__global__ __launch_bounds__(512) void k_prepB(const float* __restrict__ x,
        const float* __restrict__ hW, const float* __restrict__ gW,
        const float* __restrict__ gb, const float* __restrict__ s1W,
        unsigned short* __restrict__ ws)
{
    __shared__ __align__(16) unsigned short smem[8832];
    __shared__ float sQ[4];
    const int bid = blockIdx.x, t = threadIdx.x;
    const int w = t >> 6, lane = t & 63, l15 = lane & 15, quad = lane >> 4;

    if (bid < 256){
        const bool isM = (bid >= 128);
        unsigned short* sH = smem;
        const int br0 = (bid & 127) * 4;
        const float* kqf = (const float*)(ws + VECO) + 128;
        const float* mbf = (const float*)(ws + VECO);
        if (t < 4) sQ[t] = 0.f;
        __syncthreads();
        float qacc[4] = {0.f, 0.f, 0.f, 0.f};
        #pragma unroll
        for (int i = 0; i < 4; ++i){
            const int flat = (t + 512*i)*4;
            const int lr = i;
            const int cd = flat & 2047;
            const float4 v = *reinterpret_cast<const float4*>(x + (size_t)(br0+lr)*CD + cd);
            const int ad = (lr*16 + (cd>>7))*XSTR + lr*8 + (cd & 127);
            uint2 uh;
            uh.x = pack2(v.x, v.y); uh.y = pack2(v.z, v.w);
            *reinterpret_cast<uint2*>(sH + ad) = uh;
            if (isM){
                const float4 kq4 = *reinterpret_cast<const float4*>(kqf + (cd & 127));
                qacc[i] = v.x*kq4.x + v.y*kq4.y + v.z*kq4.z + v.w*kq4.w;
            }
        }
        if (isM){
            #pragma unroll
            for (int i = 0; i < 4; ++i){
                float s = qacc[i];
                #pragma unroll
                for (int off = 1; off < 64; off <<= 1) s += __shfl_xor(s, off);
                if (lane == 0) atomicAdd(&sQ[i], s);
            }
        }
        __syncthreads();
        if (isM){
            const float bv = mbf[w*16 + l15];
            float4v acc[4];
            #pragma unroll
            for (int mt = 0; mt < 4; ++mt){ float4v d = {bv,bv,bv,bv}; acc[mt] = d; }
            #pragma unroll
            for (int ks = 0; ks < 4; ++ks){
                const int ko = ks*32 + quad*8;
                const int bd = (w*16 + l15)*128 + ko;
                const short8 bh = *reinterpret_cast<const short8*>(ws + WMH + bd);
                const short8 bl = *reinterpret_cast<const short8*>(ws + WML + bd);
                #pragma unroll
                for (int mt = 0; mt < 4; ++mt){
                    const int ad = (mt*16 + l15)*XSTR + mt*8 + ko;
                    const short8 ah = *reinterpret_cast<const short8*>(sH + ad);
                    float4v d = acc[mt];
                    d = __builtin_amdgcn_mfma_f32_16x16x32_bf16(ah, bh, d, 0,0,0);
                    d = __builtin_amdgcn_mfma_f32_16x16x32_bf16(ah, bl, d, 0,0,0);
                    acc[mt] = d;
                }
            }
            const int f = w*16 + l15;
            #pragma unroll
            for (int mt = 0; mt < 4; ++mt)
            #pragma unroll
            for (int e = 0; e < 4; ++e){
                const int c = quad*4 + e;
                ws[MO + (size_t)(br0+mt)*CD + c*128 + f] = f2b(acc[mt][e]);
            }
            if (t < 4){
                const float s0 = ((const float*)(ws + VECO))[256];
                ((float*)(ws + QBKO))[br0 + t] = sQ[t] + 16.f*s0;
            }
        } else {
            // H: on-the-fly hW split (bit-identical to old table path)
            const int n = w*16 + l15;
            float4v acc[4];
            #pragma unroll
            for (int mt = 0; mt < 4; ++mt){ float4v z = {0.f,0.f,0.f,0.f}; acc[mt] = z; }
            #pragma unroll
            for (int ks = 0; ks < 4; ++ks){
                const int ko = ks*32 + quad*8;
                short8 bh, bl;
                #pragma unroll
                for (int j = 0; j < 8; ++j){
                    short hh, ll;
                    splitw(hW[(size_t)(ko+j)*128 + n], &hh, &ll);
                    bh[j] = hh; bl[j] = ll;
                }
                #pragma unroll
                for (int mt = 0; mt < 4; ++mt){
                    const int ad = (mt*16 + l15)*XSTR + mt*8 + ko;
                    const short8 ah = *reinterpret_cast<const short8*>(sH + ad);
                    float4v d = acc[mt];
                    d = __builtin_amdgcn_mfma_f32_16x16x32_bf16(ah, bh, d, 0,0,0);
                    d = __builtin_amdgcn_mfma_f32_16x16x32_bf16(ah, bl, d, 0,0,0);
                    acc[mt] = d;
                }
            }
            #pragma unroll
            for (int mt = 0; mt < 4; ++mt)
            #pragma unroll
            for (int e = 0; e < 4; ++e){
                const int c = quad*4 + e;
                ws[HO + (size_t)(br0+mt)*CD + c*128 + n] = f2b(acc[mt][e]);
            }
        }
    } else if (bid < 384){
        // GT[b][c*128+f][r] = sum_d gW[d,f] * x[b,r,c,d] + gb[f]; on-the-fly gW split
        unsigned short* tileB = smem;   // [r][d] stride 138
        const int gidx = bid - 256;
        const int b = gidx >> 4, cd0 = (gidx & 15)*128;
        #pragma unroll
        for (int i = 0; i < 16; ++i){
            const int idx = i*512 + t;
            const int r = idx >> 7, dd = idx & 127;
            tileB[r*138 + dd] = f2b(x[(size_t)(b*64 + r)*CD + cd0 + dd]);
        }
        __syncthreads();
        const int fA = w*16 + l15;
        float4v acc[4];
        #pragma unroll
        for (int nt = 0; nt < 4; ++nt){ float4v z = {0.f,0.f,0.f,0.f}; acc[nt] = z; }
        #pragma unroll
        for (int ks = 0; ks < 4; ++ks){
            const int ko = ks*32 + quad*8;
            short8 ah, al;
            #pragma unroll
            for (int j = 0; j < 8; ++j){
                short hh, ll;
                splitw(gW[(size_t)(ko+j)*128 + fA], &hh, &ll);
                ah[j] = hh; al[j] = ll;
            }
            #pragma unroll
            for (int nt = 0; nt < 4; ++nt){
                const short8 bb = *reinterpret_cast<const short8*>(tileB + (nt*16 + l15)*138 + ko);
                float4v d = acc[nt];
                d = __builtin_amdgcn_mfma_f32_16x16x32_bf16(ah, bb, d, 0,0,0);
                d = __builtin_amdgcn_mfma_f32_16x16x32_bf16(al, bb, d, 0,0,0);
                acc[nt] = d;
            }
        }
        #pragma unroll
        for (int nt = 0; nt < 4; ++nt)
        #pragma unroll
        for (int e = 0; e < 4; ++e){
            const int f = w*16 + quad*4 + e;
            const float val = acc[nt][e] + gb[f];
            ws[GTO + (size_t)(b*2048 + cd0 + f)*64 + nt*16 + l15] = f2b(val);
        }
    } else if (bid < 388){
        // s1W^T plain bf16 convert
        const int gid = (bid - 384)*4096 + t;
        #pragma unroll
        for (int i = 0; i < 8; ++i){
            const int g = gid + i*512;
            const int n = g >> 7, k = g & 127;
            ws[WSH + g] = f2b(s1W[k*128 + n]);
        }
    } else {
        // XT[b][cd][r] transpose from x (512 threads)
        unsigned short* tile = smem;    // [cc][r] stride 69, 128x64
        const int blk = bid - 388;      // 0..127
        const int b = blk >> 4, cd0 = (blk & 15)*128;
        #pragma unroll
        for (int i = 0; i < 16; ++i){
            const int idx = i*512 + t;
            const int r = idx >> 7, cc = idx & 127;
            tile[cc*69 + r] = f2b(x[((size_t)(b*64 + r))*CD + cd0 + cc]);
        }
        __syncthreads();
        const unsigned int base = XTO + (unsigned int)(b*2048 + cd0)*64;
        #pragma unroll
        for (int j = 0; j < 16; ++j){
            const int idx = j*512 + t;
            const int cc = idx >> 6, r = idx & 63;
            ws[base + cc*64 + r] = tile[cc*69 + r];
        }
    }
}

// =========== main fused kernel: grid (b, 126), 512 threads, PG=16 ===========
__global__ __launch_bounds__(512, 4) void k_main(
    const float* __restrict__ x, const float* __restrict__ seq_mask,
    const int* __restrict__ row, const int* __restrict__ col,
    const float* __restrict__ hb, const float* __restrict__ s1b,
    const float* __restrict__ s2W, const float* __restrict__ s2b,
    const unsigned short* __restrict__ ws, float* __restrict__ out)
{
    __shared__ __align__(16) unsigned short sX[256*XSTR + 128];
    __shared__ __align__(16) unsigned short sAl[16*72];
    __shared__ float sLog[16*LSTR];
    __shared__ float sOut[PG];
    __shared__ float sMask[16];
    __shared__ int srp[PG], scp[PG];

    const int t = threadIdx.x;
    const int w = t >> 6, lane = t & 63, l15 = lane & 15, quad = lane >> 4;
    const int b = blockIdx.x, p0 = blockIdx.y * PG;
    const float* xb = x + (size_t)b * R_ * CD;
    const unsigned short* Hb = ws + HO + (size_t)b * R_ * CD;

    if (t < PG){ srp[t] = row[p0+t]; scp[t] = col[p0+t]; sOut[t] = 0.f; }
    if (t >= 32 && t < 48) sMask[t-32] = seq_mask[b*C_ + (t-32)];
    for (int i = t; i < 1152; i += 512) sAl[i] = 0;
    for (int i = t; i < 16*LSTR; i += 512) sLog[i] = 0.f;
    __syncthreads();

    // ---- phase 1: fused stage + h-gate: x = xj + sigmoid(Hi-Hj+hb)*(xi-xj) ----
    #pragma unroll 4
    for (int i = 0; i < 16; ++i){
        const int flat = (t + 512*i)*4;
        const int p = flat >> 11, cd = flat & 2047;
        const int ri = srp[p], ci = scp[p];
        const float4 xi = *reinterpret_cast<const float4*>(xb + (size_t)ri*CD + cd);
        const float4 xj = *reinterpret_cast<const float4*>(xb + (size_t)ci*CD + cd);
        const uint2 Hi2 = *reinterpret_cast<const uint2*>(Hb + (size_t)ri*CD + cd);
        const uint2 Hj2 = *reinterpret_cast<const uint2*>(Hb + (size_t)ci*CD + cd);
        const float4 h4 = *reinterpret_cast<const float4*>(hb + (cd & 127));
        const float z0 = sigmoid_safe(lo2f(Hi2.x)  - lo2f(Hj2.x)  + h4.x);
        const float z1 = sigmoid_safe(hif2f(Hi2.x) - hif2f(Hj2.x) + h4.y);
        const float z2 = sigmoid_safe(lo2f(Hi2.y)  - lo2f(Hj2.y)  + h4.z);
        const float z3 = sigmoid_safe(hif2f(Hi2.y) - hif2f(Hj2.y) + h4.w);
        const float v0 = xj.x + z0*(xi.x - xj.x);
        const float v1 = xj.y + z1*(xi.y - xj.y);
        const float v2 = xj.z + z2*(xi.z - xj.z);
        const float v3 = xj.w + z3*(xi.w - xj.w);
        const int ad = (p*16 + (cd>>7))*XSTR + p*8 + (cd & 127);
        uint2 uv; uv.x = pack2(v0,v1); uv.y = pack2(v2,v3);
        *reinterpret_cast<uint2*>(sX + ad) = uv;
    }
    __syncthreads();

    // ---- phase 2: alpha GEMM logits[p][r] = x . M[b,r] — 8-deep bh prefetch batches ----
    {
        const int rt = w & 3, kh = w >> 2;
        const int r = rt*16 + l15;
        const unsigned short* Mr = ws + MO + ((size_t)b*64 + r)*CD + kh*1024;
        float4v d0 = {0.f,0.f,0.f,0.f}, d1 = {0.f,0.f,0.f,0.f};
        float4v d2 = {0.f,0.f,0.f,0.f}, d3 = {0.f,0.f,0.f,0.f};
        #pragma unroll
        for (int h = 0; h < 4; ++h){
            short8 bhr[8];
            #pragma unroll
            for (int u = 0; u < 8; ++u)
                bhr[u] = *reinterpret_cast<const short8*>(Mr + (h*8+u)*32 + quad*8);
            #pragma unroll
            for (int u = 0; u < 8; ++u){
                const int k = kh*1024 + (h*8+u)*32 + quad*8;
                const short8 ah = *reinterpret_cast<const short8*>(
                    sX + (l15*16 + (k>>7))*XSTR + l15*8 + (k & 127));
                if ((u&3) == 0)      d0 = __builtin_amdgcn_mfma_f32_16x16x32_bf16(ah, bhr[u], d0, 0,0,0);
                else if ((u&3) == 1) d1 = __builtin_amdgcn_mfma_f32_16x16x32_bf16(ah, bhr[u], d1, 0,0,0);
                else if ((u&3) == 2) d2 = __builtin_amdgcn_mfma_f32_16x16x32_bf16(ah, bhr[u], d2, 0,0,0);
                else                 d3 = __builtin_amdgcn_mfma_f32_16x16x32_bf16(ah, bhr[u], d3, 0,0,0);
            }
        }
        const float4v d = (d0 + d1) + (d2 + d3);
        #pragma unroll
        for (int e = 0; e < 4; ++e){
            const int pp = quad*4 + e;
            atomicAdd(&sLog[pp*LSTR + r], d[e]);
        }
    }
    __syncthreads();

    // ---- phase-3 prefetch (issued before softmax; XT/GT don't depend on it) ----
    const unsigned short* XTb = ws + XTO + (size_t)b * CD * 64;
    const unsigned short* GTb = ws + GTO + (size_t)b * CD * 64;
    short8 px0[2], px1[2], pg0[2], pg1[2];
    #pragma unroll
    for (int j = 0; j < 2; ++j){
        const int cd = w*256 + j*16 + l15;
        px0[j] = *reinterpret_cast<const short8*>(XTb + (size_t)cd*64 + quad*8);
        px1[j] = *reinterpret_cast<const short8*>(XTb + (size_t)cd*64 + 32 + quad*8);
        pg0[j] = *reinterpret_cast<const short8*>(GTb + (size_t)cd*64 + quad*8);
        pg1[j] = *reinterpret_cast<const short8*>(GTb + (size_t)cd*64 + 32 + quad*8);
    }

    // ---- masked softmax (threads 0..255: 16 lanes per pair) ----
    if (t < 256){
        const int pp = t >> 4, l = t & 15;
        const int ri = srp[pp], ci = scp[pp];
        const float* qbk = (const float*)(ws + QBKO);
        float v[4]; float m = NEG_BIG;
        #pragma unroll
        for (int k = 0; k < 4; ++k){
            const int r = l + 16*k;
            float lv = (sLog[pp*LSTR + r] + qbk[b*64 + r]) * SCALE;
            if (r == ri || r == ci) lv = NEG_BIG;
            v[k] = lv; m = fmaxf(m, lv);
        }
        #pragma unroll
        for (int s = 1; s < 16; s <<= 1) m = fmaxf(m, __shfl_xor(m, s));
        float e4[4]; float sum = 0.f;
        #pragma unroll
        for (int k = 0; k < 4; ++k){
            const int r = l + 16*k;
            const bool masked = (r == ri || r == ci);
            const float e = masked ? 0.f : __expf(fmaxf(v[k]-m, -80.f));
            e4[k] = e; sum += e;
        }
        #pragma unroll
        for (int s = 1; s < 16; s <<= 1) sum += __shfl_xor(sum, s);
        const float inv = __builtin_amdgcn_rcpf(sum);
        #pragma unroll
        for (int k = 0; k < 4; ++k) sAl[pp*72 + l + 16*k] = f2b1(e4[k]*inv);
    }
    __syncthreads();

    // ---- phase 3: fused xg + g GEMMs (K=64) + gate, 2-deep load pipeline ----
    {
        const short8 Ah0 = *reinterpret_cast<const short8*>(sAl + l15*72 + quad*8);
        const short8 Ah1 = *reinterpret_cast<const short8*>(sAl + l15*72 + 32 + quad*8);
        #pragma unroll
        for (int j = 0; j < 16; ++j){
            const int s = j & 1;
            float4v dx = {0.f,0.f,0.f,0.f}, dg = {0.f,0.f,0.f,0.f};
            dx = __builtin_amdgcn_mfma_f32_16x16x32_bf16(Ah0, px0[s], dx, 0,0,0);
            dx = __builtin_amdgcn_mfma_f32_16x16x32_bf16(Ah1, px1[s], dx, 0,0,0);
            dg = __builtin_amdgcn_mfma_f32_16x16x32_bf16(Ah0, pg0[s], dg, 0,0,0);
            dg = __builtin_amdgcn_mfma_f32_16x16x32_bf16(Ah1, pg1[s], dg, 0,0,0);
            if (j + 2 < 16){
                const int cd2 = w*256 + (j+2)*16 + l15;
                px0[s] = *reinterpret_cast<const short8*>(XTb + (size_t)cd2*64 + quad*8);
                px1[s] = *reinterpret_cast<const short8*>(XTb + (size_t)cd2*64 + 32 + quad*8);
                pg0[s] = *reinterpret_cast<const short8*>(GTb + (size_t)cd2*64 + quad*8);
                pg1[s] = *reinterpret_cast<const short8*>(GTb + (size_t)cd2*64 + 32 + quad*8);
            }
            const int cd = w*256 + j*16 + l15;
            #pragma unroll
            for (int e = 0; e < 4; ++e){
                const int pp = quad*4 + e;
                const int ad = (pp*16 + (cd>>7))*XSTR + pp*8 + (cd & 127);
                const float wv = sigmoid_safe(dg[e]);
                const float xo = b2f(sX[ad]);
                sX[ad] = f2b1((1.f - wv)*xo + wv*dx[e]);
            }
        }
    }
    __syncthreads();

    // ---- phase 4: s1-GEMM (M=256, single-bf16 weights) + tanh-gelu + reduce ----
    {
        float4v acc16[16];
        const float bv = s1b[w*16 + l15];
        #pragma unroll
        for (int mt = 0; mt < 16; ++mt){ float4v d = {bv,bv,bv,bv}; acc16[mt] = d; }
        short8 bh4[4];
        #pragma unroll
        for (int ks = 0; ks < 4; ++ks)
            bh4[ks] = *reinterpret_cast<const short8*>(ws + WSH + (w*16 + l15)*128 + ks*32 + quad*8);
        #pragma unroll
        for (int ks = 0; ks < 4; ++ks){
            const int ko = ks*32 + quad*8;
            #pragma unroll
            for (int mt = 0; mt < 16; ++mt){
                const short8 a = *reinterpret_cast<const short8*>(sX + (mt*16 + l15)*XSTR + mt*8 + ko);
                acc16[mt] = __builtin_amdgcn_mfma_f32_16x16x32_bf16(a, bh4[ks], acc16[mt], 0,0,0);
            }
        }
        const float s2v = s2W[w*16 + l15];
        const float mk0 = sMask[quad*4+0], mk1 = sMask[quad*4+1];
        const float mk2 = sMask[quad*4+2], mk3 = sMask[quad*4+3];
        float psum[16];
        #pragma unroll
        for (int mt = 0; mt < 16; ++mt){
            float s = gelu_tanh(acc16[mt][0]) * mk0;
            s += gelu_tanh(acc16[mt][1]) * mk1;
            s += gelu_tanh(acc16[mt][2]) * mk2;
            s += gelu_tanh(acc16[mt][3]) * mk3;
            psum[mt] = s * s2v;
        }
        #pragma unroll
        for (int s = 1; s < 64; s <<= 1)
            #pragma unroll
            for (int mt = 0; mt < 16; ++mt) psum[mt] += __shfl_xor(psum[mt], s);
        if (lane == 0){
            #pragma unroll
            for (int mt = 0; mt < 16; ++mt) atomicAdd(&sOut[mt], psum[mt]);
        }
    }
    __syncthreads();

    if (t < PG){
        float msum = 0.f;
        #pragma unroll
        for (int c = 0; c < 16; ++c) msum += sMask[c];
        out[(size_t)b*NPAIR + p0 + t] = sOut[t] + s2b[0]*msum;
    }
}

extern "C" void kernel_launch(void* const* d_in, const int* in_sizes, int n_in,
                              void* d_out, int out_size, void* d_ws, size_t ws_size,
                              hipStream_t stream)
{
    const float* x    = (const float*)d_in[0];
    const float* mask = (const float*)d_in[1];
    const int*   row  = (const int*)d_in[2];
    const int*   col  = (const int*)d_in[3];
    const float* hW  = (const float*)d_in[4];  const float* hb  = (const float*)d_in[5];
    const float* gW  = (const float*)d_in[6];  const float* gb  = (const float*)d_in[7];
    const float* qW  = (const float*)d_in[8];  const float* qb  = (const float*)d_in[9];
    const float* kW  = (const float*)d_in[10]; const float* kb  = (const float*)d_in[11];
    const float* s1W = (const float*)d_in[12]; const float* s1b = (const float*)d_in[13];
    const float* s2W = (const float*)d_in[14]; const float* s2b = (const float*)d_in[15];

    unsigned short* ws = (unsigned short*)d_ws;

    k_prepA<<<65, 256, 0, stream>>>(qW, qb, kW, kb, ws);
    k_prepB<<<516, 512, 0, stream>>>(x, hW, gW, gb, s1W, ws);
    k_main<<<dim3(B_, NPG), 512, 0, stream>>>(x, mask, row, col,
                                              hb, s1b, s2W, s2b,
                                              ws, (float*)d_out);
}

// Round 5
// 204.663 us; speedup vs baseline: 1.1107x; 1.1107x over previous
//
#include <hip/hip_runtime.h>
#include <hip/hip_bf16.h>
#include <math.h>

#define B_    8
#define R_    64
#define C_    16
#define D_    128
#define NPAIR 2016
#define CD    2048
#define PG    32
#define NPG   63
#define XSTR  136
#define LSTR  68
#define NEG_BIG (-1e30f)
#define SCALE 0.022097086912079608f   // 1/sqrt(2048)

typedef __attribute__((ext_vector_type(8))) short short8;
typedef __attribute__((ext_vector_type(4))) float float4v;

// ---- ws layout (ushort offsets) ----
#define WMH  0u         // P split-hi, layout [d][e]
#define WML  16384u
#define WSH  98304u     // s1W^T plain bf16 [n][k]
#define VECO 131072u    // fp32[257]: mb[0..128), kq[128..256), s0[256]
#define QBKO 131592u    // fp32[512]
#define MO   132616u    // bf16 M[b][r][2048]
#define XTO  1181192u   // bf16 XT[b][cd][64]
#define GTO  2229768u   // bf16 GT[b][cd][64]
#define HO   3278344u   // bf16 H[b][r][2048]

// fast RNE bf16 (inputs finite by construction — no NaN path)
__device__ __forceinline__ unsigned short f2b(float f){
    union { float f; unsigned int u; } v; v.f = f;
    const unsigned int r = v.u + 0x7FFFu + ((v.u >> 16) & 1u);
    return (unsigned short)(r >> 16);
}
__device__ __forceinline__ float b2f(unsigned short u){
    union { unsigned int i; float f; } v; v.i = ((unsigned int)u) << 16; return v.f;
}
__device__ __forceinline__ float lo2f(unsigned int u){
    union { unsigned int i; float f; } v; v.i = u << 16; return v.f;
}
__device__ __forceinline__ float hif2f(unsigned int u){
    union { unsigned int i; float f; } v; v.i = u & 0xffff0000u; return v.f;
}
// single-instruction packed bf16 convert (RNE, same rounding as f2b)
__device__ __forceinline__ unsigned int pack2(float a, float b){
    unsigned int r;
    asm("v_cvt_pk_bf16_f32 %0, %1, %2" : "=v"(r) : "v"(a), "v"(b));
    return r;
}
__device__ __forceinline__ unsigned short f2b1(float a){
    unsigned int r;
    asm("v_cvt_pk_bf16_f32 %0, %1, %1" : "=v"(r) : "v"(a));
    return (unsigned short)r;
}
__device__ __forceinline__ void split_bf(float v, float* hi, float* lo){
    union { float f; unsigned int u; } x; x.f = v;
    const unsigned int r = (x.u + 0x7FFFu + ((x.u >> 16) & 1u)) & 0xffff0000u;
    union { unsigned int u; float f; } h; h.u = r;
    *hi = h.f; *lo = v - h.f;
}
// split to bf16 pair directly (bit-identical to split_bf + f2b on both halves)
__device__ __forceinline__ void splitw(float v, short* h, short* l){
    union { float f; unsigned int u; } x; x.f = v;
    const unsigned int rh = (x.u + 0x7FFFu + ((x.u >> 16) & 1u)) & 0xffff0000u;
    union { unsigned int u; float f; } hf; hf.u = rh;
    *h = (short)(rh >> 16);
    *l = (short)f2b(v - hf.f);
}
// no clamp needed: exp(+inf)->inf, rcp(inf)->0 ; exp(-inf)->0 -> 1. Inputs finite.
__device__ __forceinline__ float sigmoid_safe(float x){
    return __builtin_amdgcn_rcpf(1.f + __expf(-x));
}
// tanh-GELU via sigmoid identity (empirically error-neutral here, R12/R13 data)
__device__ __forceinline__ float gelu_tanh(float x){
    const float u = x*x;
    const float g2 = x*(1.5957691216057308f + 0.07135481627159f*u);
    return x * sigmoid_safe(g2);
}

// ===== launch A (small): P split + vectors only (65 blocks) =====
__global__ __launch_bounds__(256) void k_prepA(
    const float* __restrict__ qW, const float* __restrict__ qb,
    const float* __restrict__ kW, const float* __restrict__ kb,
    unsigned short* __restrict__ ws)
{
    const int bid = blockIdx.x, t = threadIdx.x;
    if (bid < 64){
        __shared__ float sKW[2][128];
        const int e0 = bid*2;
        sKW[t>>7][t&127] = kW[(e0 + (t>>7))*128 + (t&127)];
        __syncthreads();
        const int e = t>>7, d = t&127;
        const float* qr = qW + d*128;
        const float* kr = sKW[e];
        float acc = 0.f;
        #pragma unroll 8
        for (int g = 0; g < 128; g += 4){
            const float4 qv = *reinterpret_cast<const float4*>(qr + g);
            acc += qv.x*kr[g] + qv.y*kr[g+1] + qv.z*kr[g+2] + qv.w*kr[g+3];
        }
        float hi, lo; split_bf(acc, &hi, &lo);
        ws[WMH + d*128 + (e0+e)] = f2b(hi);
        ws[WML + d*128 + (e0+e)] = f2b(lo);
    } else {
        float* vec = (float*)(ws + VECO);
        if (t < 128){
            float a1 = 0.f, a2 = 0.f;
            #pragma unroll 8
            for (int g = 0; g < 128; g += 4){
                const float4 q4 = *reinterpret_cast<const float4*>(qW + t*128 + g);
                const float4 k4 = *reinterpret_cast<const float4*>(kW + t*128 + g);
                const float4 kb4 = *reinterpret_cast<const float4*>(kb + g);
                const float4 qb4 = *reinterpret_cast<const float4*>(qb + g);
                a1 += q4.x*kb4.x + q4.y*kb4.y + q4.z*kb4.z + q4.w*kb4.w;
                a2 += k4.x*qb4.x + k4.y*qb4.y + k4.z*qb4.z + k4.w*qb4.w;
            }
            vec[t] = a1;        // mb[d]
            vec[128 + t] = a2;  // kq[e]
        } else if (t == 128){
            float a = 0.f;
            for (int g = 0; g < 128; ++g) a = fmaf(qb[g], kb[g], a);
            vec[256] = a;       // s0
        }
    }
}

// ===== launch B: [0,128) H | [128,256) M+qbk | [256,384) GT | [384,388) s1W | [388,516) XT =====
__global__ __launch_bounds__(512) void k_prepB(const float* __restrict__ x,
        const float* __restrict__ hW, const float* __restrict__ gW,
        const float* __restrict__ gb, const float* __restrict__ s1W,
        unsigned short* __restrict__ ws)
{
    __shared__ __align__(16) unsigned short smem[8832];
    __shared__ float sQ[4];
    const int bid = blockIdx.x, t = threadIdx.x;
    const int w = t >> 6, lane = t & 63, l15 = lane & 15, quad = lane >> 4;

    if (bid < 256){
        const bool isM = (bid >= 128);
        unsigned short* sH = smem;
        const int br0 = (bid & 127) * 4;
        const float* kqf = (const float*)(ws + VECO) + 128;
        const float* mbf = (const float*)(ws + VECO);
        if (t < 4) sQ[t] = 0.f;
        __syncthreads();
        float qacc[4] = {0.f, 0.f, 0.f, 0.f};
        #pragma unroll
        for (int i = 0; i < 4; ++i){
            const int flat = (t + 512*i)*4;
            const int lr = i;
            const int cd = flat & 2047;
            const float4 v = *reinterpret_cast<const float4*>(x + (size_t)(br0+lr)*CD + cd);
            const int ad = (lr*16 + (cd>>7))*XSTR + lr*8 + (cd & 127);
            uint2 uh;
            uh.x = pack2(v.x, v.y); uh.y = pack2(v.z, v.w);
            *reinterpret_cast<uint2*>(sH + ad) = uh;
            if (isM){
                const float4 kq4 = *reinterpret_cast<const float4*>(kqf + (cd & 127));
                qacc[i] = v.x*kq4.x + v.y*kq4.y + v.z*kq4.z + v.w*kq4.w;
            }
        }
        if (isM){
            #pragma unroll
            for (int i = 0; i < 4; ++i){
                float s = qacc[i];
                #pragma unroll
                for (int off = 1; off < 64; off <<= 1) s += __shfl_xor(s, off);
                if (lane == 0) atomicAdd(&sQ[i], s);
            }
        }
        __syncthreads();
        if (isM){
            const float bv = mbf[w*16 + l15];
            float4v acc[4];
            #pragma unroll
            for (int mt = 0; mt < 4; ++mt){ float4v d = {bv,bv,bv,bv}; acc[mt] = d; }
            #pragma unroll
            for (int ks = 0; ks < 4; ++ks){
                const int ko = ks*32 + quad*8;
                const int bd = (w*16 + l15)*128 + ko;
                const short8 bh = *reinterpret_cast<const short8*>(ws + WMH + bd);
                const short8 bl = *reinterpret_cast<const short8*>(ws + WML + bd);
                #pragma unroll
                for (int mt = 0; mt < 4; ++mt){
                    const int ad = (mt*16 + l15)*XSTR + mt*8 + ko;
                    const short8 ah = *reinterpret_cast<const short8*>(sH + ad);
                    float4v d = acc[mt];
                    d = __builtin_amdgcn_mfma_f32_16x16x32_bf16(ah, bh, d, 0,0,0);
                    d = __builtin_amdgcn_mfma_f32_16x16x32_bf16(ah, bl, d, 0,0,0);
                    acc[mt] = d;
                }
            }
            const int f = w*16 + l15;
            #pragma unroll
            for (int mt = 0; mt < 4; ++mt)
            #pragma unroll
            for (int e = 0; e < 4; ++e){
                const int c = quad*4 + e;
                ws[MO + (size_t)(br0+mt)*CD + c*128 + f] = f2b(acc[mt][e]);
            }
            if (t < 4){
                const float s0 = ((const float*)(ws + VECO))[256];
                ((float*)(ws + QBKO))[br0 + t] = sQ[t] + 16.f*s0;
            }
        } else {
            // H: on-the-fly hW split (bit-identical to old table path)
            const int n = w*16 + l15;
            float4v acc[4];
            #pragma unroll
            for (int mt = 0; mt < 4; ++mt){ float4v z = {0.f,0.f,0.f,0.f}; acc[mt] = z; }
            #pragma unroll
            for (int ks = 0; ks < 4; ++ks){
                const int ko = ks*32 + quad*8;
                short8 bh, bl;
                #pragma unroll
                for (int j = 0; j < 8; ++j){
                    short hh, ll;
                    splitw(hW[(size_t)(ko+j)*128 + n], &hh, &ll);
                    bh[j] = hh; bl[j] = ll;
                }
                #pragma unroll
                for (int mt = 0; mt < 4; ++mt){
                    const int ad = (mt*16 + l15)*XSTR + mt*8 + ko;
                    const short8 ah = *reinterpret_cast<const short8*>(sH + ad);
                    float4v d = acc[mt];
                    d = __builtin_amdgcn_mfma_f32_16x16x32_bf16(ah, bh, d, 0,0,0);
                    d = __builtin_amdgcn_mfma_f32_16x16x32_bf16(ah, bl, d, 0,0,0);
                    acc[mt] = d;
                }
            }
            #pragma unroll
            for (int mt = 0; mt < 4; ++mt)
            #pragma unroll
            for (int e = 0; e < 4; ++e){
                const int c = quad*4 + e;
                ws[HO + (size_t)(br0+mt)*CD + c*128 + n] = f2b(acc[mt][e]);
            }
        }
    } else if (bid < 384){
        // GT[b][c*128+f][r] = sum_d gW[d,f] * x[b,r,c,d] + gb[f]; on-the-fly gW split
        unsigned short* tileB = smem;   // [r][d] stride 138
        const int gidx = bid - 256;
        const int b = gidx >> 4, cd0 = (gidx & 15)*128;
        #pragma unroll
        for (int i = 0; i < 16; ++i){
            const int idx = i*512 + t;
            const int r = idx >> 7, dd = idx & 127;
            tileB[r*138 + dd] = f2b(x[(size_t)(b*64 + r)*CD + cd0 + dd]);
        }
        __syncthreads();
        const int fA = w*16 + l15;
        float4v acc[4];
        #pragma unroll
        for (int nt = 0; nt < 4; ++nt){ float4v z = {0.f,0.f,0.f,0.f}; acc[nt] = z; }
        #pragma unroll
        for (int ks = 0; ks < 4; ++ks){
            const int ko = ks*32 + quad*8;
            short8 ah, al;
            #pragma unroll
            for (int j = 0; j < 8; ++j){
                short hh, ll;
                splitw(gW[(size_t)(ko+j)*128 + fA], &hh, &ll);
                ah[j] = hh; al[j] = ll;
            }
            #pragma unroll
            for (int nt = 0; nt < 4; ++nt){
                const short8 bb = *reinterpret_cast<const short8*>(tileB + (nt*16 + l15)*138 + ko);
                float4v d = acc[nt];
                d = __builtin_amdgcn_mfma_f32_16x16x32_bf16(ah, bb, d, 0,0,0);
                d = __builtin_amdgcn_mfma_f32_16x16x32_bf16(al, bb, d, 0,0,0);
                acc[nt] = d;
            }
        }
        #pragma unroll
        for (int nt = 0; nt < 4; ++nt)
        #pragma unroll
        for (int e = 0; e < 4; ++e){
            const int f = w*16 + quad*4 + e;
            const float val = acc[nt][e] + gb[f];
            ws[GTO + (size_t)(b*2048 + cd0 + f)*64 + nt*16 + l15] = f2b(val);
        }
    } else if (bid < 388){
        // s1W^T plain bf16 convert
        const int gid = (bid - 384)*4096 + t;
        #pragma unroll
        for (int i = 0; i < 8; ++i){
            const int g = gid + i*512;
            const int n = g >> 7, k = g & 127;
            ws[WSH + g] = f2b(s1W[k*128 + n]);
        }
    } else {
        // XT[b][cd][r] transpose from x (512 threads)
        unsigned short* tile = smem;    // [cc][r] stride 69, 128x64
        const int blk = bid - 388;      // 0..127
        const int b = blk >> 4, cd0 = (blk & 15)*128;
        #pragma unroll
        for (int i = 0; i < 16; ++i){
            const int idx = i*512 + t;
            const int r = idx >> 7, cc = idx & 127;
            tile[cc*69 + r] = f2b(x[((size_t)(b*64 + r))*CD + cd0 + cc]);
        }
        __syncthreads();
        const unsigned int base = XTO + (unsigned int)(b*2048 + cd0)*64;
        #pragma unroll
        for (int j = 0; j < 16; ++j){
            const int idx = j*512 + t;
            const int cc = idx >> 6, r = idx & 63;
            ws[base + cc*64 + r] = tile[cc*69 + r];
        }
    }
}

// =========== main fused kernel: grid (b, 63), 1024 threads, PG=32 ===========
// PG=32/1024t: per-pair panel traffic and load-stall events halve vs PG=16
// (R2 showed PG=8 doubles them and regresses 1:1); per-thread VALU/MFMA
// unchanged; 153.5KB LDS -> 1 block/CU x 16 waves (same 50% occ cap as 2x8).
__global__ __launch_bounds__(1024, 4) void k_main(
    const float* __restrict__ x, const float* __restrict__ seq_mask,
    const int* __restrict__ row, const int* __restrict__ col,
    const float* __restrict__ hb, const float* __restrict__ s1b,
    const float* __restrict__ s2W, const float* __restrict__ s2b,
    const unsigned short* __restrict__ ws, float* __restrict__ out)
{
    __shared__ __align__(16) unsigned short sX[512*XSTR + 256];
    __shared__ __align__(16) unsigned short sAl[32*72];
    __shared__ float sLog[32*LSTR];
    __shared__ float sOut[PG];
    __shared__ float sMask[16];
    __shared__ int srp[PG], scp[PG];

    const int t = threadIdx.x;
    const int w = t >> 6, lane = t & 63, l15 = lane & 15, quad = lane >> 4;
    const int b = blockIdx.x, p0 = blockIdx.y * PG;
    const float* xb = x + (size_t)b * R_ * CD;
    const unsigned short* Hb = ws + HO + (size_t)b * R_ * CD;

    if (t < PG){ srp[t] = row[p0+t]; scp[t] = col[p0+t]; sOut[t] = 0.f; }
    if (t >= 32 && t < 48) sMask[t-32] = seq_mask[b*C_ + (t-32)];
    for (int i = t; i < 32*72; i += 1024) sAl[i] = 0;
    for (int i = t; i < 32*LSTR; i += 1024) sLog[i] = 0.f;
    __syncthreads();

    // ---- phase 1: fused stage + h-gate: x = xj + sigmoid(Hi-Hj+hb)*(xi-xj) ----
    #pragma unroll 4
    for (int i = 0; i < 16; ++i){
        const int flat = (t + 1024*i)*4;
        const int p = flat >> 11, cd = flat & 2047;
        const int ri = srp[p], ci = scp[p];
        const float4 xi = *reinterpret_cast<const float4*>(xb + (size_t)ri*CD + cd);
        const float4 xj = *reinterpret_cast<const float4*>(xb + (size_t)ci*CD + cd);
        const uint2 Hi2 = *reinterpret_cast<const uint2*>(Hb + (size_t)ri*CD + cd);
        const uint2 Hj2 = *reinterpret_cast<const uint2*>(Hb + (size_t)ci*CD + cd);
        const float4 h4 = *reinterpret_cast<const float4*>(hb + (cd & 127));
        const float z0 = sigmoid_safe(lo2f(Hi2.x)  - lo2f(Hj2.x)  + h4.x);
        const float z1 = sigmoid_safe(hif2f(Hi2.x) - hif2f(Hj2.x) + h4.y);
        const float z2 = sigmoid_safe(lo2f(Hi2.y)  - lo2f(Hj2.y)  + h4.z);
        const float z3 = sigmoid_safe(hif2f(Hi2.y) - hif2f(Hj2.y) + h4.w);
        const float v0 = xj.x + z0*(xi.x - xj.x);
        const float v1 = xj.y + z1*(xi.y - xj.y);
        const float v2 = xj.z + z2*(xi.z - xj.z);
        const float v3 = xj.w + z3*(xi.w - xj.w);
        const int ad = (p*16 + (cd>>7))*XSTR + p*8 + (cd & 127);
        uint2 uv; uv.x = pack2(v0,v1); uv.y = pack2(v2,v3);
        *reinterpret_cast<uint2*>(sX + ad) = uv;
    }
    __syncthreads();

    // ---- phase 2: alpha GEMM logits[p][r] = x . M[b,r]
    // 16 waves = (rt: 4 r-tiles) x (kh: 4 K-quarters); 2 pair-tiles per wave ----
    {
        const int rt = w & 3, kh = w >> 2;
        const int r = rt*16 + l15;
        const unsigned short* Mr = ws + MO + ((size_t)b*64 + r)*CD + kh*512;
        float4v d0a = {0.f,0.f,0.f,0.f}, d0b = {0.f,0.f,0.f,0.f};
        float4v d1a = {0.f,0.f,0.f,0.f}, d1b = {0.f,0.f,0.f,0.f};
        #pragma unroll
        for (int h = 0; h < 2; ++h){
            short8 bhr[8];
            #pragma unroll
            for (int u = 0; u < 8; ++u)
                bhr[u] = *reinterpret_cast<const short8*>(Mr + (h*8+u)*32 + quad*8);
            #pragma unroll
            for (int u = 0; u < 8; ++u){
                const int k = kh*512 + (h*8+u)*32 + quad*8;
                const int khi = k >> 7, klo = k & 127;
                const int pA = l15, pB = 16 + l15;
                const short8 ahA = *reinterpret_cast<const short8*>(
                    sX + (pA*16 + khi)*XSTR + pA*8 + klo);
                const short8 ahB = *reinterpret_cast<const short8*>(
                    sX + (pB*16 + khi)*XSTR + pB*8 + klo);
                if (u & 1){
                    d0b = __builtin_amdgcn_mfma_f32_16x16x32_bf16(ahA, bhr[u], d0b, 0,0,0);
                    d1b = __builtin_amdgcn_mfma_f32_16x16x32_bf16(ahB, bhr[u], d1b, 0,0,0);
                } else {
                    d0a = __builtin_amdgcn_mfma_f32_16x16x32_bf16(ahA, bhr[u], d0a, 0,0,0);
                    d1a = __builtin_amdgcn_mfma_f32_16x16x32_bf16(ahB, bhr[u], d1a, 0,0,0);
                }
            }
        }
        const float4v dA = d0a + d0b;
        const float4v dB = d1a + d1b;
        #pragma unroll
        for (int e = 0; e < 4; ++e){
            const int pp = quad*4 + e;
            atomicAdd(&sLog[pp*LSTR + r], dA[e]);
            atomicAdd(&sLog[(16+pp)*LSTR + r], dB[e]);
        }
    }
    __syncthreads();

    // ---- phase-3 prefetch (issued before softmax; XT/GT don't depend on it) ----
    const unsigned short* XTb = ws + XTO + (size_t)b * CD * 64;
    const unsigned short* GTb = ws + GTO + (size_t)b * CD * 64;
    short8 px0[2], px1[2], pg0[2], pg1[2];
    #pragma unroll
    for (int j = 0; j < 2; ++j){
        const int cd = w*128 + j*16 + l15;
        px0[j] = *reinterpret_cast<const short8*>(XTb + (size_t)cd*64 + quad*8);
        px1[j] = *reinterpret_cast<const short8*>(XTb + (size_t)cd*64 + 32 + quad*8);
        pg0[j] = *reinterpret_cast<const short8*>(GTb + (size_t)cd*64 + quad*8);
        pg1[j] = *reinterpret_cast<const short8*>(GTb + (size_t)cd*64 + 32 + quad*8);
    }

    // ---- masked softmax (threads 0..511: 16 lanes per pair) ----
    if (t < 512){
        const int pp = t >> 4, l = t & 15;
        const int ri = srp[pp], ci = scp[pp];
        const float* qbk = (const float*)(ws + QBKO);
        float v[4]; float m = NEG_BIG;
        #pragma unroll
        for (int k = 0; k < 4; ++k){
            const int r = l + 16*k;
            float lv = (sLog[pp*LSTR + r] + qbk[b*64 + r]) * SCALE;
            if (r == ri || r == ci) lv = NEG_BIG;
            v[k] = lv; m = fmaxf(m, lv);
        }
        #pragma unroll
        for (int s = 1; s < 16; s <<= 1) m = fmaxf(m, __shfl_xor(m, s));
        float e4[4]; float sum = 0.f;
        #pragma unroll
        for (int k = 0; k < 4; ++k){
            const int r = l + 16*k;
            const bool masked = (r == ri || r == ci);
            const float e = masked ? 0.f : __expf(fmaxf(v[k]-m, -80.f));
            e4[k] = e; sum += e;
        }
        #pragma unroll
        for (int s = 1; s < 16; s <<= 1) sum += __shfl_xor(sum, s);
        const float inv = __builtin_amdgcn_rcpf(sum);
        #pragma unroll
        for (int k = 0; k < 4; ++k) sAl[pp*72 + l + 16*k] = f2b1(e4[k]*inv);
    }
    __syncthreads();

    // ---- phase 3: fused xg + g GEMMs (K=64) + gate, 2 pair-tiles, 2-deep pipeline ----
    {
        const short8 AhA0 = *reinterpret_cast<const short8*>(sAl + l15*72 + quad*8);
        const short8 AhA1 = *reinterpret_cast<const short8*>(sAl + l15*72 + 32 + quad*8);
        const short8 AhB0 = *reinterpret_cast<const short8*>(sAl + (16+l15)*72 + quad*8);
        const short8 AhB1 = *reinterpret_cast<const short8*>(sAl + (16+l15)*72 + 32 + quad*8);
        #pragma unroll
        for (int j = 0; j < 8; ++j){
            const int s = j & 1;
            float4v dxA = {0.f,0.f,0.f,0.f}, dgA = {0.f,0.f,0.f,0.f};
            float4v dxB = {0.f,0.f,0.f,0.f}, dgB = {0.f,0.f,0.f,0.f};
            dxA = __builtin_amdgcn_mfma_f32_16x16x32_bf16(AhA0, px0[s], dxA, 0,0,0);
            dxA = __builtin_amdgcn_mfma_f32_16x16x32_bf16(AhA1, px1[s], dxA, 0,0,0);
            dgA = __builtin_amdgcn_mfma_f32_16x16x32_bf16(AhA0, pg0[s], dgA, 0,0,0);
            dgA = __builtin_amdgcn_mfma_f32_16x16x32_bf16(AhA1, pg1[s], dgA, 0,0,0);
            dxB = __builtin_amdgcn_mfma_f32_16x16x32_bf16(AhB0, px0[s], dxB, 0,0,0);
            dxB = __builtin_amdgcn_mfma_f32_16x16x32_bf16(AhB1, px1[s], dxB, 0,0,0);
            dgB = __builtin_amdgcn_mfma_f32_16x16x32_bf16(AhB0, pg0[s], dgB, 0,0,0);
            dgB = __builtin_amdgcn_mfma_f32_16x16x32_bf16(AhB1, pg1[s], dgB, 0,0,0);
            if (j + 2 < 8){
                const int cd2 = w*128 + (j+2)*16 + l15;
                px0[s] = *reinterpret_cast<const short8*>(XTb + (size_t)cd2*64 + quad*8);
                px1[s] = *reinterpret_cast<const short8*>(XTb + (size_t)cd2*64 + 32 + quad*8);
                pg0[s] = *reinterpret_cast<const short8*>(GTb + (size_t)cd2*64 + quad*8);
                pg1[s] = *reinterpret_cast<const short8*>(GTb + (size_t)cd2*64 + 32 + quad*8);
            }
            const int cd = w*128 + j*16 + l15;
            const int khi = cd >> 7, klo = cd & 127;
            #pragma unroll
            for (int e = 0; e < 4; ++e){
                const int ppA = quad*4 + e;
                const int adA = (ppA*16 + khi)*XSTR + ppA*8 + klo;
                const float wvA = sigmoid_safe(dgA[e]);
                const float xoA = b2f(sX[adA]);
                sX[adA] = f2b1((1.f - wvA)*xoA + wvA*dxA[e]);
                const int ppB = 16 + quad*4 + e;
                const int adB = (ppB*16 + khi)*XSTR + ppB*8 + klo;
                const float wvB = sigmoid_safe(dgB[e]);
                const float xoB = b2f(sX[adB]);
                sX[adB] = f2b1((1.f - wvB)*xoB + wvB*dxB[e]);
            }
        }
    }
    __syncthreads();

    // ---- phase 4: s1-GEMM (M=512, single-bf16 weights) + tanh-gelu + reduce
    // 16 waves = (mh: 2 row-halves) x (nw: 8 n-tiles) ----
    {
        const int mh = w >> 3, nw = w & 7;
        float4v acc16[16];
        const float bv = s1b[nw*16 + l15];
        #pragma unroll
        for (int mt = 0; mt < 16; ++mt){ float4v d = {bv,bv,bv,bv}; acc16[mt] = d; }
        short8 bh4[4];
        #pragma unroll
        for (int ks = 0; ks < 4; ++ks)
            bh4[ks] = *reinterpret_cast<const short8*>(ws + WSH + (nw*16 + l15)*128 + ks*32 + quad*8);
        #pragma unroll
        for (int ks = 0; ks < 4; ++ks){
            const int ko = ks*32 + quad*8;
            #pragma unroll
            for (int mt = 0; mt < 16; ++mt){
                const int p = mh*16 + mt;
                const short8 a = *reinterpret_cast<const short8*>(sX + (p*16 + l15)*XSTR + p*8 + ko);
                acc16[mt] = __builtin_amdgcn_mfma_f32_16x16x32_bf16(a, bh4[ks], acc16[mt], 0,0,0);
            }
        }
        const float s2v = s2W[nw*16 + l15];
        const float mk0 = sMask[quad*4+0], mk1 = sMask[quad*4+1];
        const float mk2 = sMask[quad*4+2], mk3 = sMask[quad*4+3];
        float psum[16];
        #pragma unroll
        for (int mt = 0; mt < 16; ++mt){
            float s = gelu_tanh(acc16[mt][0]) * mk0;
            s += gelu_tanh(acc16[mt][1]) * mk1;
            s += gelu_tanh(acc16[mt][2]) * mk2;
            s += gelu_tanh(acc16[mt][3]) * mk3;
            psum[mt] = s * s2v;
        }
        #pragma unroll
        for (int s = 1; s < 64; s <<= 1)
            #pragma unroll
            for (int mt = 0; mt < 16; ++mt) psum[mt] += __shfl_xor(psum[mt], s);
        if (lane == 0){
            #pragma unroll
            for (int mt = 0; mt < 16; ++mt) atomicAdd(&sOut[mh*16 + mt], psum[mt]);
        }
    }
    __syncthreads();

    if (t < PG){
        float msum = 0.f;
        #pragma unroll
        for (int c = 0; c < 16; ++c) msum += sMask[c];
        out[(size_t)b*NPAIR + p0 + t] = sOut[t] + s2b[0]*msum;
    }
}

extern "C" void kernel_launch(void* const* d_in, const int* in_sizes, int n_in,
                              void* d_out, int out_size, void* d_ws, size_t ws_size,
                              hipStream_t stream)
{
    const float* x    = (const float*)d_in[0];
    const float* mask = (const float*)d_in[1];
    const int*   row  = (const int*)d_in[2];
    const int*   col  = (const int*)d_in[3];
    const float* hW  = (const float*)d_in[4];  const float* hb  = (const float*)d_in[5];
    const float* gW  = (const float*)d_in[6];  const float* gb  = (const float*)d_in[7];
    const float* qW  = (const float*)d_in[8];  const float* qb  = (const float*)d_in[9];
    const float* kW  = (const float*)d_in[10]; const float* kb  = (const float*)d_in[11];
    const float* s1W = (const float*)d_in[12]; const float* s1b = (const float*)d_in[13];
    const float* s2W = (const float*)d_in[14]; const float* s2b = (const float*)d_in[15];

    unsigned short* ws = (unsigned short*)d_ws;

    k_prepA<<<65, 256, 0, stream>>>(qW, qb, kW, kb, ws);
    k_prepB<<<516, 512, 0, stream>>>(x, hW, gW, gb, s1W, ws);
    k_main<<<dim3(B_, NPG), 1024, 0, stream>>>(x, mask, row, col,
                                               hb, s1b, s2W, s2b,
                                               ws, (float*)d_out);
}

// Round 6
// 204.150 us; speedup vs baseline: 1.1135x; 1.0025x over previous
//
#include <hip/hip_runtime.h>
#include <hip/hip_bf16.h>
#include <math.h>

#define B_    8
#define R_    64
#define C_    16
#define D_    128
#define NPAIR 2016
#define CD    2048
#define PG    32
#define NPG   63
#define XSTR  136
#define LSTR  68
#define NEG_BIG (-1e30f)
#define SCALE 0.022097086912079608f   // 1/sqrt(2048)

typedef __attribute__((ext_vector_type(8))) short short8;
typedef __attribute__((ext_vector_type(4))) float float4v;

// ---- ws layout (ushort offsets) ----
#define WMH  0u         // P split-hi, layout [d][e]
#define WML  16384u
#define WSH  98304u     // s1W^T plain bf16 [n][k]
#define VECO 131072u    // fp32[257]: mb[0..128), kq[128..256), s0[256]
#define QBKO 131592u    // fp32[512]
#define MO   132616u    // bf16 M[b][r][2048]
#define XTO  1181192u   // bf16 XT[b][cd][64]
#define GTO  2229768u   // bf16 GT[b][cd][64]
#define HO   3278344u   // bf16 H[b][r][2048]

// fast RNE bf16 (inputs finite by construction — no NaN path)
__device__ __forceinline__ unsigned short f2b(float f){
    union { float f; unsigned int u; } v; v.f = f;
    const unsigned int r = v.u + 0x7FFFu + ((v.u >> 16) & 1u);
    return (unsigned short)(r >> 16);
}
__device__ __forceinline__ float b2f(unsigned short u){
    union { unsigned int i; float f; } v; v.i = ((unsigned int)u) << 16; return v.f;
}
__device__ __forceinline__ float lo2f(unsigned int u){
    union { unsigned int i; float f; } v; v.i = u << 16; return v.f;
}
__device__ __forceinline__ float hif2f(unsigned int u){
    union { unsigned int i; float f; } v; v.i = u & 0xffff0000u; return v.f;
}
// single-instruction packed bf16 convert (RNE, same rounding as f2b)
__device__ __forceinline__ unsigned int pack2(float a, float b){
    unsigned int r;
    asm("v_cvt_pk_bf16_f32 %0, %1, %2" : "=v"(r) : "v"(a), "v"(b));
    return r;
}
__device__ __forceinline__ unsigned short f2b1(float a){
    unsigned int r;
    asm("v_cvt_pk_bf16_f32 %0, %1, %1" : "=v"(r) : "v"(a));
    return (unsigned short)r;
}
__device__ __forceinline__ void split_bf(float v, float* hi, float* lo){
    union { float f; unsigned int u; } x; x.f = v;
    const unsigned int r = (x.u + 0x7FFFu + ((x.u >> 16) & 1u)) & 0xffff0000u;
    union { unsigned int u; float f; } h; h.u = r;
    *hi = h.f; *lo = v - h.f;
}
// split to bf16 pair directly (bit-identical to split_bf + f2b on both halves)
__device__ __forceinline__ void splitw(float v, short* h, short* l){
    union { float f; unsigned int u; } x; x.f = v;
    const unsigned int rh = (x.u + 0x7FFFu + ((x.u >> 16) & 1u)) & 0xffff0000u;
    union { unsigned int u; float f; } hf; hf.u = rh;
    *h = (short)(rh >> 16);
    *l = (short)f2b(v - hf.f);
}
// no clamp needed: exp(+inf)->inf, rcp(inf)->0 ; exp(-inf)->0 -> 1. Inputs finite.
__device__ __forceinline__ float sigmoid_safe(float x){
    return __builtin_amdgcn_rcpf(1.f + __expf(-x));
}
// tanh-GELU via sigmoid identity (empirically error-neutral here, R12/R13 data)
__device__ __forceinline__ float gelu_tanh(float x){
    const float u = x*x;
    const float g2 = x*(1.5957691216057308f + 0.07135481627159f*u);
    return x * sigmoid_safe(g2);
}

// ===== launch A (small): P split + vectors only (65 blocks) =====
__global__ __launch_bounds__(256) void k_prepA(
    const float* __restrict__ qW, const float* __restrict__ qb,
    const float* __restrict__ kW, const float* __restrict__ kb,
    unsigned short* __restrict__ ws)
{
    const int bid = blockIdx.x, t = threadIdx.x;
    if (bid < 64){
        __shared__ float sKW[2][128];
        const int e0 = bid*2;
        sKW[t>>7][t&127] = kW[(e0 + (t>>7))*128 + (t&127)];
        __syncthreads();
        const int e = t>>7, d = t&127;
        const float* qr = qW + d*128;
        const float* kr = sKW[e];
        float acc = 0.f;
        #pragma unroll 8
        for (int g = 0; g < 128; g += 4){
            const float4 qv = *reinterpret_cast<const float4*>(qr + g);
            acc += qv.x*kr[g] + qv.y*kr[g+1] + qv.z*kr[g+2] + qv.w*kr[g+3];
        }
        float hi, lo; split_bf(acc, &hi, &lo);
        ws[WMH + d*128 + (e0+e)] = f2b(hi);
        ws[WML + d*128 + (e0+e)] = f2b(lo);
    } else {
        float* vec = (float*)(ws + VECO);
        if (t < 128){
            float a1 = 0.f, a2 = 0.f;
            #pragma unroll 8
            for (int g = 0; g < 128; g += 4){
                const float4 q4 = *reinterpret_cast<const float4*>(qW + t*128 + g);
                const float4 k4 = *reinterpret_cast<const float4*>(kW + t*128 + g);
                const float4 kb4 = *reinterpret_cast<const float4*>(kb + g);
                const float4 qb4 = *reinterpret_cast<const float4*>(qb + g);
                a1 += q4.x*kb4.x + q4.y*kb4.y + q4.z*kb4.z + q4.w*kb4.w;
                a2 += k4.x*qb4.x + k4.y*qb4.y + k4.z*qb4.z + k4.w*qb4.w;
            }
            vec[t] = a1;        // mb[d]
            vec[128 + t] = a2;  // kq[e]
        } else if (t == 128){
            float a = 0.f;
            for (int g = 0; g < 128; ++g) a = fmaf(qb[g], kb[g], a);
            vec[256] = a;       // s0
        }
    }
}

// ===== launch B (fused): [0,128) H+M | [128,256) GT+XT | [256,260) s1W cvt =====
// H+M share the same 4 staged x rows (x read once, not twice);
// XT is the transpose of GT's staged tile (emitted from LDS, no extra x read).
__global__ __launch_bounds__(512) void k_prepB(const float* __restrict__ x,
        const float* __restrict__ hW, const float* __restrict__ gW,
        const float* __restrict__ gb, const float* __restrict__ s1W,
        unsigned short* __restrict__ ws)
{
    __shared__ __align__(16) unsigned short smem[8832];
    __shared__ float sQ[4];
    const int bid = blockIdx.x, t = threadIdx.x;
    const int w = t >> 6, lane = t & 63, l15 = lane & 15, quad = lane >> 4;

    if (bid < 128){
        // ---- fused H + M for rows br0..br0+3 ----
        unsigned short* sH = smem;
        const int br0 = bid * 4;
        const float* kqf = (const float*)(ws + VECO) + 128;
        const float* mbf = (const float*)(ws + VECO);
        if (t < 4) sQ[t] = 0.f;
        __syncthreads();
        float qacc[4] = {0.f, 0.f, 0.f, 0.f};
        #pragma unroll
        for (int i = 0; i < 4; ++i){
            const int flat = (t + 512*i)*4;
            const int lr = i;
            const int cd = flat & 2047;
            const float4 v = *reinterpret_cast<const float4*>(x + (size_t)(br0+lr)*CD + cd);
            const int ad = (lr*16 + (cd>>7))*XSTR + lr*8 + (cd & 127);
            uint2 uh;
            uh.x = pack2(v.x, v.y); uh.y = pack2(v.z, v.w);
            *reinterpret_cast<uint2*>(sH + ad) = uh;
            const float4 kq4 = *reinterpret_cast<const float4*>(kqf + (cd & 127));
            qacc[i] = v.x*kq4.x + v.y*kq4.y + v.z*kq4.z + v.w*kq4.w;
        }
        #pragma unroll
        for (int i = 0; i < 4; ++i){
            float s = qacc[i];
            #pragma unroll
            for (int off = 1; off < 64; off <<= 1) s += __shfl_xor(s, off);
            if (lane == 0) atomicAdd(&sQ[i], s);
        }
        __syncthreads();
        // --- M pass (P tables) ---
        {
            const float bv = mbf[w*16 + l15];
            float4v acc[4];
            #pragma unroll
            for (int mt = 0; mt < 4; ++mt){ float4v d = {bv,bv,bv,bv}; acc[mt] = d; }
            #pragma unroll
            for (int ks = 0; ks < 4; ++ks){
                const int ko = ks*32 + quad*8;
                const int bd = (w*16 + l15)*128 + ko;
                const short8 bh = *reinterpret_cast<const short8*>(ws + WMH + bd);
                const short8 bl = *reinterpret_cast<const short8*>(ws + WML + bd);
                #pragma unroll
                for (int mt = 0; mt < 4; ++mt){
                    const int ad = (mt*16 + l15)*XSTR + mt*8 + ko;
                    const short8 ah = *reinterpret_cast<const short8*>(sH + ad);
                    float4v d = acc[mt];
                    d = __builtin_amdgcn_mfma_f32_16x16x32_bf16(ah, bh, d, 0,0,0);
                    d = __builtin_amdgcn_mfma_f32_16x16x32_bf16(ah, bl, d, 0,0,0);
                    acc[mt] = d;
                }
            }
            const int f = w*16 + l15;
            #pragma unroll
            for (int mt = 0; mt < 4; ++mt)
            #pragma unroll
            for (int e = 0; e < 4; ++e){
                const int c = quad*4 + e;
                ws[MO + (size_t)(br0+mt)*CD + c*128 + f] = f2b(acc[mt][e]);
            }
            if (t < 4){
                const float s0 = ((const float*)(ws + VECO))[256];
                ((float*)(ws + QBKO))[br0 + t] = sQ[t] + 16.f*s0;
            }
        }
        // --- H pass (on-the-fly hW split) ---
        {
            const int n = w*16 + l15;
            float4v acc[4];
            #pragma unroll
            for (int mt = 0; mt < 4; ++mt){ float4v z = {0.f,0.f,0.f,0.f}; acc[mt] = z; }
            #pragma unroll
            for (int ks = 0; ks < 4; ++ks){
                const int ko = ks*32 + quad*8;
                short8 bh, bl;
                #pragma unroll
                for (int j = 0; j < 8; ++j){
                    short hh, ll;
                    splitw(hW[(size_t)(ko+j)*128 + n], &hh, &ll);
                    bh[j] = hh; bl[j] = ll;
                }
                #pragma unroll
                for (int mt = 0; mt < 4; ++mt){
                    const int ad = (mt*16 + l15)*XSTR + mt*8 + ko;
                    const short8 ah = *reinterpret_cast<const short8*>(sH + ad);
                    float4v d = acc[mt];
                    d = __builtin_amdgcn_mfma_f32_16x16x32_bf16(ah, bh, d, 0,0,0);
                    d = __builtin_amdgcn_mfma_f32_16x16x32_bf16(ah, bl, d, 0,0,0);
                    acc[mt] = d;
                }
            }
            #pragma unroll
            for (int mt = 0; mt < 4; ++mt)
            #pragma unroll
            for (int e = 0; e < 4; ++e){
                const int c = quad*4 + e;
                ws[HO + (size_t)(br0+mt)*CD + c*128 + n] = f2b(acc[mt][e]);
            }
        }
    } else if (bid < 256){
        // ---- fused GT + XT for (b, cd0) tile ----
        unsigned short* tileB = smem;   // [r][d] stride 138
        const int gidx = bid - 128;
        const int b = gidx >> 4, cd0 = (gidx & 15)*128;
        #pragma unroll
        for (int i = 0; i < 16; ++i){
            const int idx = i*512 + t;
            const int r = idx >> 7, dd = idx & 127;
            tileB[r*138 + dd] = f2b(x[(size_t)(b*64 + r)*CD + cd0 + dd]);
        }
        __syncthreads();
        // XT = transpose of tileB (coalesced global writes)
        {
            const unsigned int base = XTO + (unsigned int)(b*2048 + cd0)*64;
            #pragma unroll
            for (int j = 0; j < 16; ++j){
                const int idx = j*512 + t;
                const int cc = idx >> 6, r = idx & 63;
                ws[base + cc*64 + r] = tileB[r*138 + cc];
            }
        }
        // GT MFMA (on-the-fly gW split)
        const int fA = w*16 + l15;
        float4v acc[4];
        #pragma unroll
        for (int nt = 0; nt < 4; ++nt){ float4v z = {0.f,0.f,0.f,0.f}; acc[nt] = z; }
        #pragma unroll
        for (int ks = 0; ks < 4; ++ks){
            const int ko = ks*32 + quad*8;
            short8 ah, al;
            #pragma unroll
            for (int j = 0; j < 8; ++j){
                short hh, ll;
                splitw(gW[(size_t)(ko+j)*128 + fA], &hh, &ll);
                ah[j] = hh; al[j] = ll;
            }
            #pragma unroll
            for (int nt = 0; nt < 4; ++nt){
                const short8 bb = *reinterpret_cast<const short8*>(tileB + (nt*16 + l15)*138 + ko);
                float4v d = acc[nt];
                d = __builtin_amdgcn_mfma_f32_16x16x32_bf16(ah, bb, d, 0,0,0);
                d = __builtin_amdgcn_mfma_f32_16x16x32_bf16(al, bb, d, 0,0,0);
                acc[nt] = d;
            }
        }
        #pragma unroll
        for (int nt = 0; nt < 4; ++nt)
        #pragma unroll
        for (int e = 0; e < 4; ++e){
            const int f = w*16 + quad*4 + e;
            const float val = acc[nt][e] + gb[f];
            ws[GTO + (size_t)(b*2048 + cd0 + f)*64 + nt*16 + l15] = f2b(val);
        }
    } else {
        // s1W^T plain bf16 convert
        const int gid = (bid - 256)*4096 + t;
        #pragma unroll
        for (int i = 0; i < 8; ++i){
            const int g = gid + i*512;
            const int n = g >> 7, k = g & 127;
            ws[WSH + g] = f2b(s1W[k*128 + n]);
        }
    }
}

// =========== main fused kernel: grid (b, 63), 1024 threads, PG=32 ===========
// PG=32/1024t: per-pair panel traffic and load-stall events halve vs PG=16
// (R2 showed PG=8 doubles them and regresses 1:1); per-thread VALU/MFMA
// unchanged; 153.5KB LDS -> 1 block/CU x 16 waves (same 50% occ cap as 2x8).
__global__ __launch_bounds__(1024, 4) void k_main(
    const float* __restrict__ x, const float* __restrict__ seq_mask,
    const int* __restrict__ row, const int* __restrict__ col,
    const float* __restrict__ hb, const float* __restrict__ s1b,
    const float* __restrict__ s2W, const float* __restrict__ s2b,
    const unsigned short* __restrict__ ws, float* __restrict__ out)
{
    __shared__ __align__(16) unsigned short sX[512*XSTR + 256];
    __shared__ __align__(16) unsigned short sAl[32*72];
    __shared__ float sLog[32*LSTR];
    __shared__ float sOut[PG];
    __shared__ float sMask[16];
    __shared__ int srp[PG], scp[PG];

    const int t = threadIdx.x;
    const int w = t >> 6, lane = t & 63, l15 = lane & 15, quad = lane >> 4;
    const int b = blockIdx.x, p0 = blockIdx.y * PG;
    const float* xb = x + (size_t)b * R_ * CD;
    const unsigned short* Hb = ws + HO + (size_t)b * R_ * CD;

    if (t < PG){ srp[t] = row[p0+t]; scp[t] = col[p0+t]; sOut[t] = 0.f; }
    if (t >= 32 && t < 48) sMask[t-32] = seq_mask[b*C_ + (t-32)];
    for (int i = t; i < 32*72; i += 1024) sAl[i] = 0;
    for (int i = t; i < 32*LSTR; i += 1024) sLog[i] = 0.f;
    __syncthreads();

    // ---- phase 1: fused stage + h-gate: x = xj + sigmoid(Hi-Hj+hb)*(xi-xj) ----
    #pragma unroll 4
    for (int i = 0; i < 16; ++i){
        const int flat = (t + 1024*i)*4;
        const int p = flat >> 11, cd = flat & 2047;
        const int ri = srp[p], ci = scp[p];
        const float4 xi = *reinterpret_cast<const float4*>(xb + (size_t)ri*CD + cd);
        const float4 xj = *reinterpret_cast<const float4*>(xb + (size_t)ci*CD + cd);
        const uint2 Hi2 = *reinterpret_cast<const uint2*>(Hb + (size_t)ri*CD + cd);
        const uint2 Hj2 = *reinterpret_cast<const uint2*>(Hb + (size_t)ci*CD + cd);
        const float4 h4 = *reinterpret_cast<const float4*>(hb + (cd & 127));
        const float z0 = sigmoid_safe(lo2f(Hi2.x)  - lo2f(Hj2.x)  + h4.x);
        const float z1 = sigmoid_safe(hif2f(Hi2.x) - hif2f(Hj2.x) + h4.y);
        const float z2 = sigmoid_safe(lo2f(Hi2.y)  - lo2f(Hj2.y)  + h4.z);
        const float z3 = sigmoid_safe(hif2f(Hi2.y) - hif2f(Hj2.y) + h4.w);
        const float v0 = xj.x + z0*(xi.x - xj.x);
        const float v1 = xj.y + z1*(xi.y - xj.y);
        const float v2 = xj.z + z2*(xi.z - xj.z);
        const float v3 = xj.w + z3*(xi.w - xj.w);
        const int ad = (p*16 + (cd>>7))*XSTR + p*8 + (cd & 127);
        uint2 uv; uv.x = pack2(v0,v1); uv.y = pack2(v2,v3);
        *reinterpret_cast<uint2*>(sX + ad) = uv;
    }
    __syncthreads();

    // ---- phase 2: alpha GEMM logits[p][r] = x . M[b,r]
    // 16 waves = (rt: 4 r-tiles) x (kh: 4 K-quarters); 2 pair-tiles per wave ----
    {
        const int rt = w & 3, kh = w >> 2;
        const int r = rt*16 + l15;
        const unsigned short* Mr = ws + MO + ((size_t)b*64 + r)*CD + kh*512;
        float4v d0a = {0.f,0.f,0.f,0.f}, d0b = {0.f,0.f,0.f,0.f};
        float4v d1a = {0.f,0.f,0.f,0.f}, d1b = {0.f,0.f,0.f,0.f};
        #pragma unroll
        for (int h = 0; h < 2; ++h){
            short8 bhr[8];
            #pragma unroll
            for (int u = 0; u < 8; ++u)
                bhr[u] = *reinterpret_cast<const short8*>(Mr + (h*8+u)*32 + quad*8);
            #pragma unroll
            for (int u = 0; u < 8; ++u){
                const int k = kh*512 + (h*8+u)*32 + quad*8;
                const int khi = k >> 7, klo = k & 127;
                const int pA = l15, pB = 16 + l15;
                const short8 ahA = *reinterpret_cast<const short8*>(
                    sX + (pA*16 + khi)*XSTR + pA*8 + klo);
                const short8 ahB = *reinterpret_cast<const short8*>(
                    sX + (pB*16 + khi)*XSTR + pB*8 + klo);
                if (u & 1){
                    d0b = __builtin_amdgcn_mfma_f32_16x16x32_bf16(ahA, bhr[u], d0b, 0,0,0);
                    d1b = __builtin_amdgcn_mfma_f32_16x16x32_bf16(ahB, bhr[u], d1b, 0,0,0);
                } else {
                    d0a = __builtin_amdgcn_mfma_f32_16x16x32_bf16(ahA, bhr[u], d0a, 0,0,0);
                    d1a = __builtin_amdgcn_mfma_f32_16x16x32_bf16(ahB, bhr[u], d1a, 0,0,0);
                }
            }
        }
        const float4v dA = d0a + d0b;
        const float4v dB = d1a + d1b;
        #pragma unroll
        for (int e = 0; e < 4; ++e){
            const int pp = quad*4 + e;
            atomicAdd(&sLog[pp*LSTR + r], dA[e]);
            atomicAdd(&sLog[(16+pp)*LSTR + r], dB[e]);
        }
    }
    __syncthreads();

    // ---- phase-3 prefetch (issued before softmax; XT/GT don't depend on it) ----
    const unsigned short* XTb = ws + XTO + (size_t)b * CD * 64;
    const unsigned short* GTb = ws + GTO + (size_t)b * CD * 64;
    short8 px0[2], px1[2], pg0[2], pg1[2];
    #pragma unroll
    for (int j = 0; j < 2; ++j){
        const int cd = w*128 + j*16 + l15;
        px0[j] = *reinterpret_cast<const short8*>(XTb + (size_t)cd*64 + quad*8);
        px1[j] = *reinterpret_cast<const short8*>(XTb + (size_t)cd*64 + 32 + quad*8);
        pg0[j] = *reinterpret_cast<const short8*>(GTb + (size_t)cd*64 + quad*8);
        pg1[j] = *reinterpret_cast<const short8*>(GTb + (size_t)cd*64 + 32 + quad*8);
    }

    // ---- masked softmax (threads 0..511: 16 lanes per pair) ----
    if (t < 512){
        const int pp = t >> 4, l = t & 15;
        const int ri = srp[pp], ci = scp[pp];
        const float* qbk = (const float*)(ws + QBKO);
        float v[4]; float m = NEG_BIG;
        #pragma unroll
        for (int k = 0; k < 4; ++k){
            const int r = l + 16*k;
            float lv = (sLog[pp*LSTR + r] + qbk[b*64 + r]) * SCALE;
            if (r == ri || r == ci) lv = NEG_BIG;
            v[k] = lv; m = fmaxf(m, lv);
        }
        #pragma unroll
        for (int s = 1; s < 16; s <<= 1) m = fmaxf(m, __shfl_xor(m, s));
        float e4[4]; float sum = 0.f;
        #pragma unroll
        for (int k = 0; k < 4; ++k){
            const int r = l + 16*k;
            const bool masked = (r == ri || r == ci);
            const float e = masked ? 0.f : __expf(fmaxf(v[k]-m, -80.f));
            e4[k] = e; sum += e;
        }
        #pragma unroll
        for (int s = 1; s < 16; s <<= 1) sum += __shfl_xor(sum, s);
        const float inv = __builtin_amdgcn_rcpf(sum);
        #pragma unroll
        for (int k = 0; k < 4; ++k) sAl[pp*72 + l + 16*k] = f2b1(e4[k]*inv);
    }
    __syncthreads();

    // ---- phase 3: fused xg + g GEMMs (K=64) + gate, 2 pair-tiles, 2-deep pipeline ----
    {
        const short8 AhA0 = *reinterpret_cast<const short8*>(sAl + l15*72 + quad*8);
        const short8 AhA1 = *reinterpret_cast<const short8*>(sAl + l15*72 + 32 + quad*8);
        const short8 AhB0 = *reinterpret_cast<const short8*>(sAl + (16+l15)*72 + quad*8);
        const short8 AhB1 = *reinterpret_cast<const short8*>(sAl + (16+l15)*72 + 32 + quad*8);
        #pragma unroll
        for (int j = 0; j < 8; ++j){
            const int s = j & 1;
            float4v dxA = {0.f,0.f,0.f,0.f}, dgA = {0.f,0.f,0.f,0.f};
            float4v dxB = {0.f,0.f,0.f,0.f}, dgB = {0.f,0.f,0.f,0.f};
            dxA = __builtin_amdgcn_mfma_f32_16x16x32_bf16(AhA0, px0[s], dxA, 0,0,0);
            dxA = __builtin_amdgcn_mfma_f32_16x16x32_bf16(AhA1, px1[s], dxA, 0,0,0);
            dgA = __builtin_amdgcn_mfma_f32_16x16x32_bf16(AhA0, pg0[s], dgA, 0,0,0);
            dgA = __builtin_amdgcn_mfma_f32_16x16x32_bf16(AhA1, pg1[s], dgA, 0,0,0);
            dxB = __builtin_amdgcn_mfma_f32_16x16x32_bf16(AhB0, px0[s], dxB, 0,0,0);
            dxB = __builtin_amdgcn_mfma_f32_16x16x32_bf16(AhB1, px1[s], dxB, 0,0,0);
            dgB = __builtin_amdgcn_mfma_f32_16x16x32_bf16(AhB0, pg0[s], dgB, 0,0,0);
            dgB = __builtin_amdgcn_mfma_f32_16x16x32_bf16(AhB1, pg1[s], dgB, 0,0,0);
            if (j + 2 < 8){
                const int cd2 = w*128 + (j+2)*16 + l15;
                px0[s] = *reinterpret_cast<const short8*>(XTb + (size_t)cd2*64 + quad*8);
                px1[s] = *reinterpret_cast<const short8*>(XTb + (size_t)cd2*64 + 32 + quad*8);
                pg0[s] = *reinterpret_cast<const short8*>(GTb + (size_t)cd2*64 + quad*8);
                pg1[s] = *reinterpret_cast<const short8*>(GTb + (size_t)cd2*64 + 32 + quad*8);
            }
            const int cd = w*128 + j*16 + l15;
            const int khi = cd >> 7, klo = cd & 127;
            #pragma unroll
            for (int e = 0; e < 4; ++e){
                const int ppA = quad*4 + e;
                const int adA = (ppA*16 + khi)*XSTR + ppA*8 + klo;
                const float wvA = sigmoid_safe(dgA[e]);
                const float xoA = b2f(sX[adA]);
                sX[adA] = f2b1((1.f - wvA)*xoA + wvA*dxA[e]);
                const int ppB = 16 + quad*4 + e;
                const int adB = (ppB*16 + khi)*XSTR + ppB*8 + klo;
                const float wvB = sigmoid_safe(dgB[e]);
                const float xoB = b2f(sX[adB]);
                sX[adB] = f2b1((1.f - wvB)*xoB + wvB*dxB[e]);
            }
        }
    }
    __syncthreads();

    // ---- phase 4: s1-GEMM (M=512, single-bf16 weights) + tanh-gelu + reduce
    // 16 waves = (mh: 2 row-halves) x (nw: 8 n-tiles) ----
    {
        const int mh = w >> 3, nw = w & 7;
        float4v acc16[16];
        const float bv = s1b[nw*16 + l15];
        #pragma unroll
        for (int mt = 0; mt < 16; ++mt){ float4v d = {bv,bv,bv,bv}; acc16[mt] = d; }
        short8 bh4[4];
        #pragma unroll
        for (int ks = 0; ks < 4; ++ks)
            bh4[ks] = *reinterpret_cast<const short8*>(ws + WSH + (nw*16 + l15)*128 + ks*32 + quad*8);
        #pragma unroll
        for (int ks = 0; ks < 4; ++ks){
            const int ko = ks*32 + quad*8;
            #pragma unroll
            for (int mt = 0; mt < 16; ++mt){
                const int p = mh*16 + mt;
                const short8 a = *reinterpret_cast<const short8*>(sX + (p*16 + l15)*XSTR + p*8 + ko);
                acc16[mt] = __builtin_amdgcn_mfma_f32_16x16x32_bf16(a, bh4[ks], acc16[mt], 0,0,0);
            }
        }
        const float s2v = s2W[nw*16 + l15];
        const float mk0 = sMask[quad*4+0], mk1 = sMask[quad*4+1];
        const float mk2 = sMask[quad*4+2], mk3 = sMask[quad*4+3];
        float psum[16];
        #pragma unroll
        for (int mt = 0; mt < 16; ++mt){
            float s = gelu_tanh(acc16[mt][0]) * mk0;
            s += gelu_tanh(acc16[mt][1]) * mk1;
            s += gelu_tanh(acc16[mt][2]) * mk2;
            s += gelu_tanh(acc16[mt][3]) * mk3;
            psum[mt] = s * s2v;
        }
        #pragma unroll
        for (int s = 1; s < 64; s <<= 1)
            #pragma unroll
            for (int mt = 0; mt < 16; ++mt) psum[mt] += __shfl_xor(psum[mt], s);
        if (lane == 0){
            #pragma unroll
            for (int mt = 0; mt < 16; ++mt) atomicAdd(&sOut[mh*16 + mt], psum[mt]);
        }
    }
    __syncthreads();

    if (t < PG){
        float msum = 0.f;
        #pragma unroll
        for (int c = 0; c < 16; ++c) msum += sMask[c];
        out[(size_t)b*NPAIR + p0 + t] = sOut[t] + s2b[0]*msum;
    }
}

extern "C" void kernel_launch(void* const* d_in, const int* in_sizes, int n_in,
                              void* d_out, int out_size, void* d_ws, size_t ws_size,
                              hipStream_t stream)
{
    const float* x    = (const float*)d_in[0];
    const float* mask = (const float*)d_in[1];
    const int*   row  = (const int*)d_in[2];
    const int*   col  = (const int*)d_in[3];
    const float* hW  = (const float*)d_in[4];  const float* hb  = (const float*)d_in[5];
    const float* gW  = (const float*)d_in[6];  const float* gb  = (const float*)d_in[7];
    const float* qW  = (const float*)d_in[8];  const float* qb  = (const float*)d_in[9];
    const float* kW  = (const float*)d_in[10]; const float* kb  = (const float*)d_in[11];
    const float* s1W = (const float*)d_in[12]; const float* s1b = (const float*)d_in[13];
    const float* s2W = (const float*)d_in[14]; const float* s2b = (const float*)d_in[15];

    unsigned short* ws = (unsigned short*)d_ws;

    k_prepA<<<65, 256, 0, stream>>>(qW, qb, kW, kb, ws);
    k_prepB<<<260, 512, 0, stream>>>(x, hW, gW, gb, s1W, ws);
    k_main<<<dim3(B_, NPG), 1024, 0, stream>>>(x, mask, row, col,
                                               hb, s1b, s2W, s2b,
                                               ws, (float*)d_out);
}

// Round 7
// 196.671 us; speedup vs baseline: 1.1558x; 1.0380x over previous
//
#include <hip/hip_runtime.h>
#include <hip/hip_bf16.h>
#include <math.h>

#define B_    8
#define R_    64
#define C_    16
#define D_    128
#define NPAIR 2016
#define CD    2048
#define PG    32
#define NPG   63
#define XSTR  136
#define LSTR  68
#define NEG_BIG (-1e30f)
#define SCALE 0.022097086912079608f   // 1/sqrt(2048)

typedef __attribute__((ext_vector_type(8))) short short8;
typedef __attribute__((ext_vector_type(4))) float float4v;

// ---- ws layout (ushort offsets) ----
#define WMH  0u         // P split-hi, layout [d][e]
#define WML  16384u
#define WSH  98304u     // s1W^T plain bf16 [n][k]
#define VECO 131072u    // fp32[257]: mb[0..128), kq[128..256), s0[256]
#define QBKO 131592u    // fp32[512]
#define MO   132616u    // bf16 M[b][r][2048]
#define XTO  1181192u   // bf16 XT[b][cd][64]
#define GTO  2229768u   // bf16 GT[b][cd][64]
#define HO   3278344u   // bf16 H[b][r][2048]

// fast RNE bf16 (inputs finite by construction — no NaN path)
__device__ __forceinline__ unsigned short f2b(float f){
    union { float f; unsigned int u; } v; v.f = f;
    const unsigned int r = v.u + 0x7FFFu + ((v.u >> 16) & 1u);
    return (unsigned short)(r >> 16);
}
__device__ __forceinline__ float b2f(unsigned short u){
    union { unsigned int i; float f; } v; v.i = ((unsigned int)u) << 16; return v.f;
}
__device__ __forceinline__ float lo2f(unsigned int u){
    union { unsigned int i; float f; } v; v.i = u << 16; return v.f;
}
__device__ __forceinline__ float hif2f(unsigned int u){
    union { unsigned int i; float f; } v; v.i = u & 0xffff0000u; return v.f;
}
// single-instruction packed bf16 convert (RNE, same rounding as f2b)
__device__ __forceinline__ unsigned int pack2(float a, float b){
    unsigned int r;
    asm("v_cvt_pk_bf16_f32 %0, %1, %2" : "=v"(r) : "v"(a), "v"(b));
    return r;
}
__device__ __forceinline__ unsigned short f2b1(float a){
    unsigned int r;
    asm("v_cvt_pk_bf16_f32 %0, %1, %1" : "=v"(r) : "v"(a));
    return (unsigned short)r;
}
__device__ __forceinline__ void split_bf(float v, float* hi, float* lo){
    union { float f; unsigned int u; } x; x.f = v;
    const unsigned int r = (x.u + 0x7FFFu + ((x.u >> 16) & 1u)) & 0xffff0000u;
    union { unsigned int u; float f; } h; h.u = r;
    *hi = h.f; *lo = v - h.f;
}
// split to bf16 pair directly (bit-identical to split_bf + f2b on both halves)
__device__ __forceinline__ void splitw(float v, short* h, short* l){
    union { float f; unsigned int u; } x; x.f = v;
    const unsigned int rh = (x.u + 0x7FFFu + ((x.u >> 16) & 1u)) & 0xffff0000u;
    union { unsigned int u; float f; } hf; hf.u = rh;
    *h = (short)(rh >> 16);
    *l = (short)f2b(v - hf.f);
}
// no clamp needed: exp(+inf)->inf, rcp(inf)->0 ; exp(-inf)->0 -> 1. Inputs finite.
__device__ __forceinline__ float sigmoid_safe(float x){
    return __builtin_amdgcn_rcpf(1.f + __expf(-x));
}
// tanh-GELU via sigmoid identity (empirically error-neutral here, R12/R13 data)
__device__ __forceinline__ float gelu_tanh(float x){
    const float u = x*x;
    const float g2 = x*(1.5957691216057308f + 0.07135481627159f*u);
    return x * sigmoid_safe(g2);
}

// ===== launch A (small): P split + vectors only (65 blocks) =====
__global__ __launch_bounds__(256) void k_prepA(
    const float* __restrict__ qW, const float* __restrict__ qb,
    const float* __restrict__ kW, const float* __restrict__ kb,
    unsigned short* __restrict__ ws)
{
    const int bid = blockIdx.x, t = threadIdx.x;
    if (bid < 64){
        __shared__ float sKW[2][128];
        const int e0 = bid*2;
        sKW[t>>7][t&127] = kW[(e0 + (t>>7))*128 + (t&127)];
        __syncthreads();
        const int e = t>>7, d = t&127;
        const float* qr = qW + d*128;
        const float* kr = sKW[e];
        float acc = 0.f;
        #pragma unroll 8
        for (int g = 0; g < 128; g += 4){
            const float4 qv = *reinterpret_cast<const float4*>(qr + g);
            acc += qv.x*kr[g] + qv.y*kr[g+1] + qv.z*kr[g+2] + qv.w*kr[g+3];
        }
        float hi, lo; split_bf(acc, &hi, &lo);
        ws[WMH + d*128 + (e0+e)] = f2b(hi);
        ws[WML + d*128 + (e0+e)] = f2b(lo);
    } else {
        float* vec = (float*)(ws + VECO);
        if (t < 128){
            float a1 = 0.f, a2 = 0.f;
            #pragma unroll 8
            for (int g = 0; g < 128; g += 4){
                const float4 q4 = *reinterpret_cast<const float4*>(qW + t*128 + g);
                const float4 k4 = *reinterpret_cast<const float4*>(kW + t*128 + g);
                const float4 kb4 = *reinterpret_cast<const float4*>(kb + g);
                const float4 qb4 = *reinterpret_cast<const float4*>(qb + g);
                a1 += q4.x*kb4.x + q4.y*kb4.y + q4.z*kb4.z + q4.w*kb4.w;
                a2 += k4.x*qb4.x + k4.y*qb4.y + k4.z*qb4.z + k4.w*qb4.w;
            }
            vec[t] = a1;        // mb[d]
            vec[128 + t] = a2;  // kq[e]
        } else if (t == 128){
            float a = 0.f;
            for (int g = 0; g < 128; ++g) a = fmaf(qb[g], kb[g], a);
            vec[256] = a;       // s0
        }
    }
}

// ===== launch B (fused): [0,128) H+M | [128,256) GT+XT | [256,260) s1W cvt =====
__global__ __launch_bounds__(512) void k_prepB(const float* __restrict__ x,
        const float* __restrict__ hW, const float* __restrict__ gW,
        const float* __restrict__ gb, const float* __restrict__ s1W,
        unsigned short* __restrict__ ws)
{
    __shared__ __align__(16) unsigned short smem[8832];
    __shared__ float sQ[4];
    const int bid = blockIdx.x, t = threadIdx.x;
    const int w = t >> 6, lane = t & 63, l15 = lane & 15, quad = lane >> 4;

    if (bid < 128){
        // ---- fused H + M for rows br0..br0+3 ----
        unsigned short* sH = smem;
        const int br0 = bid * 4;
        const float* kqf = (const float*)(ws + VECO) + 128;
        const float* mbf = (const float*)(ws + VECO);
        if (t < 4) sQ[t] = 0.f;
        __syncthreads();
        float qacc[4] = {0.f, 0.f, 0.f, 0.f};
        #pragma unroll
        for (int i = 0; i < 4; ++i){
            const int flat = (t + 512*i)*4;
            const int lr = i;
            const int cd = flat & 2047;
            const float4 v = *reinterpret_cast<const float4*>(x + (size_t)(br0+lr)*CD + cd);
            const int ad = (lr*16 + (cd>>7))*XSTR + lr*8 + (cd & 127);
            uint2 uh;
            uh.x = pack2(v.x, v.y); uh.y = pack2(v.z, v.w);
            *reinterpret_cast<uint2*>(sH + ad) = uh;
            const float4 kq4 = *reinterpret_cast<const float4*>(kqf + (cd & 127));
            qacc[i] = v.x*kq4.x + v.y*kq4.y + v.z*kq4.z + v.w*kq4.w;
        }
        #pragma unroll
        for (int i = 0; i < 4; ++i){
            float s = qacc[i];
            #pragma unroll
            for (int off = 1; off < 64; off <<= 1) s += __shfl_xor(s, off);
            if (lane == 0) atomicAdd(&sQ[i], s);
        }
        __syncthreads();
        // --- M pass (P tables) ---
        {
            const float bv = mbf[w*16 + l15];
            float4v acc[4];
            #pragma unroll
            for (int mt = 0; mt < 4; ++mt){ float4v d = {bv,bv,bv,bv}; acc[mt] = d; }
            #pragma unroll
            for (int ks = 0; ks < 4; ++ks){
                const int ko = ks*32 + quad*8;
                const int bd = (w*16 + l15)*128 + ko;
                const short8 bh = *reinterpret_cast<const short8*>(ws + WMH + bd);
                const short8 bl = *reinterpret_cast<const short8*>(ws + WML + bd);
                #pragma unroll
                for (int mt = 0; mt < 4; ++mt){
                    const int ad = (mt*16 + l15)*XSTR + mt*8 + ko;
                    const short8 ah = *reinterpret_cast<const short8*>(sH + ad);
                    float4v d = acc[mt];
                    d = __builtin_amdgcn_mfma_f32_16x16x32_bf16(ah, bh, d, 0,0,0);
                    d = __builtin_amdgcn_mfma_f32_16x16x32_bf16(ah, bl, d, 0,0,0);
                    acc[mt] = d;
                }
            }
            const int f = w*16 + l15;
            #pragma unroll
            for (int mt = 0; mt < 4; ++mt)
            #pragma unroll
            for (int e = 0; e < 4; ++e){
                const int c = quad*4 + e;
                ws[MO + (size_t)(br0+mt)*CD + c*128 + f] = f2b(acc[mt][e]);
            }
            if (t < 4){
                const float s0 = ((const float*)(ws + VECO))[256];
                ((float*)(ws + QBKO))[br0 + t] = sQ[t] + 16.f*s0;
            }
        }
        // --- H pass (on-the-fly hW split) ---
        {
            const int n = w*16 + l15;
            float4v acc[4];
            #pragma unroll
            for (int mt = 0; mt < 4; ++mt){ float4v z = {0.f,0.f,0.f,0.f}; acc[mt] = z; }
            #pragma unroll
            for (int ks = 0; ks < 4; ++ks){
                const int ko = ks*32 + quad*8;
                short8 bh, bl;
                #pragma unroll
                for (int j = 0; j < 8; ++j){
                    short hh, ll;
                    splitw(hW[(size_t)(ko+j)*128 + n], &hh, &ll);
                    bh[j] = hh; bl[j] = ll;
                }
                #pragma unroll
                for (int mt = 0; mt < 4; ++mt){
                    const int ad = (mt*16 + l15)*XSTR + mt*8 + ko;
                    const short8 ah = *reinterpret_cast<const short8*>(sH + ad);
                    float4v d = acc[mt];
                    d = __builtin_amdgcn_mfma_f32_16x16x32_bf16(ah, bh, d, 0,0,0);
                    d = __builtin_amdgcn_mfma_f32_16x16x32_bf16(ah, bl, d, 0,0,0);
                    acc[mt] = d;
                }
            }
            #pragma unroll
            for (int mt = 0; mt < 4; ++mt)
            #pragma unroll
            for (int e = 0; e < 4; ++e){
                const int c = quad*4 + e;
                ws[HO + (size_t)(br0+mt)*CD + c*128 + n] = f2b(acc[mt][e]);
            }
        }
    } else if (bid < 256){
        // ---- fused GT + XT for (b, cd0) tile ----
        unsigned short* tileB = smem;   // [r][d] stride 138
        const int gidx = bid - 128;
        const int b = gidx >> 4, cd0 = (gidx & 15)*128;
        #pragma unroll
        for (int i = 0; i < 16; ++i){
            const int idx = i*512 + t;
            const int r = idx >> 7, dd = idx & 127;
            tileB[r*138 + dd] = f2b(x[(size_t)(b*64 + r)*CD + cd0 + dd]);
        }
        __syncthreads();
        // XT = transpose of tileB (coalesced global writes)
        {
            const unsigned int base = XTO + (unsigned int)(b*2048 + cd0)*64;
            #pragma unroll
            for (int j = 0; j < 16; ++j){
                const int idx = j*512 + t;
                const int cc = idx >> 6, r = idx & 63;
                ws[base + cc*64 + r] = tileB[r*138 + cc];
            }
        }
        // GT MFMA (on-the-fly gW split)
        const int fA = w*16 + l15;
        float4v acc[4];
        #pragma unroll
        for (int nt = 0; nt < 4; ++nt){ float4v z = {0.f,0.f,0.f,0.f}; acc[nt] = z; }
        #pragma unroll
        for (int ks = 0; ks < 4; ++ks){
            const int ko = ks*32 + quad*8;
            short8 ah, al;
            #pragma unroll
            for (int j = 0; j < 8; ++j){
                short hh, ll;
                splitw(gW[(size_t)(ko+j)*128 + fA], &hh, &ll);
                ah[j] = hh; al[j] = ll;
            }
            #pragma unroll
            for (int nt = 0; nt < 4; ++nt){
                const short8 bb = *reinterpret_cast<const short8*>(tileB + (nt*16 + l15)*138 + ko);
                float4v d = acc[nt];
                d = __builtin_amdgcn_mfma_f32_16x16x32_bf16(ah, bb, d, 0,0,0);
                d = __builtin_amdgcn_mfma_f32_16x16x32_bf16(al, bb, d, 0,0,0);
                acc[nt] = d;
            }
        }
        #pragma unroll
        for (int nt = 0; nt < 4; ++nt)
        #pragma unroll
        for (int e = 0; e < 4; ++e){
            const int f = w*16 + quad*4 + e;
            const float val = acc[nt][e] + gb[f];
            ws[GTO + (size_t)(b*2048 + cd0 + f)*64 + nt*16 + l15] = f2b(val);
        }
    } else {
        // s1W^T plain bf16 convert
        const int gid = (bid - 256)*4096 + t;
        #pragma unroll
        for (int i = 0; i < 8; ++i){
            const int g = gid + i*512;
            const int n = g >> 7, k = g & 127;
            ws[WSH + g] = f2b(s1W[k*128 + n]);
        }
    }
}

// =========== main fused kernel: grid (b, 63), 1024 threads, PG=32 ===========
// 1 block/CU (LDS 153.6KB). Cross-phase register prefetch: M-half-0 before
// phase 1, XT/GT before softmax+atomics, s1W before phase 3 — spends the
// spare VGPR file (was 64/128) on latency hiding across barriers.
__global__ __launch_bounds__(1024, 4) void k_main(
    const float* __restrict__ x, const float* __restrict__ seq_mask,
    const int* __restrict__ row, const int* __restrict__ col,
    const float* __restrict__ hb, const float* __restrict__ s1b,
    const float* __restrict__ s2W, const float* __restrict__ s2b,
    const unsigned short* __restrict__ ws, float* __restrict__ out)
{
    __shared__ __align__(16) unsigned short sX[512*XSTR + 256];
    __shared__ __align__(16) unsigned short sAl[32*72];
    __shared__ float sLog[32*LSTR];
    __shared__ float sOut[PG];
    __shared__ float sMask[16];
    __shared__ int srp[PG], scp[PG];

    const int t = threadIdx.x;
    const int w = t >> 6, lane = t & 63, l15 = lane & 15, quad = lane >> 4;
    const int b = blockIdx.x, p0 = blockIdx.y * PG;
    const float* xb = x + (size_t)b * R_ * CD;
    const unsigned short* Hb = ws + HO + (size_t)b * R_ * CD;

    // ---- phase-2 B-panel prefetch, half 0 (independent of phase 1) ----
    const int rt = w & 3, kh = w >> 2;
    const int r2 = rt*16 + l15;
    const unsigned short* Mr = ws + MO + ((size_t)b*64 + r2)*CD + kh*512;
    short8 bhr0[8];
    #pragma unroll
    for (int u = 0; u < 8; ++u)
        bhr0[u] = *reinterpret_cast<const short8*>(Mr + u*32 + quad*8);

    if (t < PG){ srp[t] = row[p0+t]; scp[t] = col[p0+t]; sOut[t] = 0.f; }
    if (t >= 32 && t < 48) sMask[t-32] = seq_mask[b*C_ + (t-32)];
    for (int i = t; i < 32*LSTR; i += 1024) sLog[i] = 0.f;
    __syncthreads();

    // ---- phase 1: fused stage + h-gate, 8 elem/iter ----
    #pragma unroll
    for (int i = 0; i < 8; ++i){
        const int flat = (t + 1024*i)*8;
        const int p = flat >> 11, cd = flat & 2047;
        const int ri = srp[p], ci = scp[p];
        const float* xip = xb + (size_t)ri*CD + cd;
        const float* xjp = xb + (size_t)ci*CD + cd;
        const float4 xi0 = *reinterpret_cast<const float4*>(xip);
        const float4 xi1 = *reinterpret_cast<const float4*>(xip + 4);
        const float4 xj0 = *reinterpret_cast<const float4*>(xjp);
        const float4 xj1 = *reinterpret_cast<const float4*>(xjp + 4);
        const uint4 Hi4 = *reinterpret_cast<const uint4*>(Hb + (size_t)ri*CD + cd);
        const uint4 Hj4 = *reinterpret_cast<const uint4*>(Hb + (size_t)ci*CD + cd);
        const float4 h40 = *reinterpret_cast<const float4*>(hb + (cd & 127));
        const float4 h41 = *reinterpret_cast<const float4*>(hb + (cd & 127) + 4);
        const float z0 = sigmoid_safe(lo2f(Hi4.x)  - lo2f(Hj4.x)  + h40.x);
        const float z1 = sigmoid_safe(hif2f(Hi4.x) - hif2f(Hj4.x) + h40.y);
        const float z2 = sigmoid_safe(lo2f(Hi4.y)  - lo2f(Hj4.y)  + h40.z);
        const float z3 = sigmoid_safe(hif2f(Hi4.y) - hif2f(Hj4.y) + h40.w);
        const float z4 = sigmoid_safe(lo2f(Hi4.z)  - lo2f(Hj4.z)  + h41.x);
        const float z5 = sigmoid_safe(hif2f(Hi4.z) - hif2f(Hj4.z) + h41.y);
        const float z6 = sigmoid_safe(lo2f(Hi4.w)  - lo2f(Hj4.w)  + h41.z);
        const float z7 = sigmoid_safe(hif2f(Hi4.w) - hif2f(Hj4.w) + h41.w);
        const float v0 = xj0.x + z0*(xi0.x - xj0.x);
        const float v1 = xj0.y + z1*(xi0.y - xj0.y);
        const float v2 = xj0.z + z2*(xi0.z - xj0.z);
        const float v3 = xj0.w + z3*(xi0.w - xj0.w);
        const float v4 = xj1.x + z4*(xi1.x - xj1.x);
        const float v5 = xj1.y + z5*(xi1.y - xj1.y);
        const float v6 = xj1.z + z6*(xi1.z - xj1.z);
        const float v7 = xj1.w + z7*(xi1.w - xj1.w);
        const int ad = (p*16 + (cd>>7))*XSTR + p*8 + (cd & 127);
        uint4 uv;
        uv.x = pack2(v0,v1); uv.y = pack2(v2,v3);
        uv.z = pack2(v4,v5); uv.w = pack2(v6,v7);
        *reinterpret_cast<uint4*>(sX + ad) = uv;
    }
    __syncthreads();

    // ---- phase 3 stream pointers (prefetch issued mid-phase-2) ----
    const unsigned short* XTb = ws + XTO + (size_t)b * CD * 64;
    const unsigned short* GTb = ws + GTO + (size_t)b * CD * 64;
    short8 px0[2], px1[2], pg0[2], pg1[2];

    // ---- phase 2: alpha GEMM logits[p][r] = x . M[b,r] ----
    {
        // issue half-1 B loads first
        short8 bhr1[8];
        #pragma unroll
        for (int u = 0; u < 8; ++u)
            bhr1[u] = *reinterpret_cast<const short8*>(Mr + (8+u)*32 + quad*8);
        float4v d0a = {0.f,0.f,0.f,0.f}, d0b = {0.f,0.f,0.f,0.f};
        float4v d1a = {0.f,0.f,0.f,0.f}, d1b = {0.f,0.f,0.f,0.f};
        #pragma unroll
        for (int u = 0; u < 8; ++u){
            const int k = kh*512 + u*32 + quad*8;
            const int khi = k >> 7, klo = k & 127;
            const short8 ahA = *reinterpret_cast<const short8*>(
                sX + (l15*16 + khi)*XSTR + l15*8 + klo);
            const short8 ahB = *reinterpret_cast<const short8*>(
                sX + ((16+l15)*16 + khi)*XSTR + (16+l15)*8 + klo);
            if (u & 1){
                d0b = __builtin_amdgcn_mfma_f32_16x16x32_bf16(ahA, bhr0[u], d0b, 0,0,0);
                d1b = __builtin_amdgcn_mfma_f32_16x16x32_bf16(ahB, bhr0[u], d1b, 0,0,0);
            } else {
                d0a = __builtin_amdgcn_mfma_f32_16x16x32_bf16(ahA, bhr0[u], d0a, 0,0,0);
                d1a = __builtin_amdgcn_mfma_f32_16x16x32_bf16(ahB, bhr0[u], d1a, 0,0,0);
            }
        }
        // phase-3 prefetch: overlaps half-1 MFMAs + barrier + softmax
        #pragma unroll
        for (int j = 0; j < 2; ++j){
            const int cd = w*128 + j*16 + l15;
            px0[j] = *reinterpret_cast<const short8*>(XTb + (size_t)cd*64 + quad*8);
            px1[j] = *reinterpret_cast<const short8*>(XTb + (size_t)cd*64 + 32 + quad*8);
            pg0[j] = *reinterpret_cast<const short8*>(GTb + (size_t)cd*64 + quad*8);
            pg1[j] = *reinterpret_cast<const short8*>(GTb + (size_t)cd*64 + 32 + quad*8);
        }
        #pragma unroll
        for (int u = 0; u < 8; ++u){
            const int k = kh*512 + (8+u)*32 + quad*8;
            const int khi = k >> 7, klo = k & 127;
            const short8 ahA = *reinterpret_cast<const short8*>(
                sX + (l15*16 + khi)*XSTR + l15*8 + klo);
            const short8 ahB = *reinterpret_cast<const short8*>(
                sX + ((16+l15)*16 + khi)*XSTR + (16+l15)*8 + klo);
            if (u & 1){
                d0b = __builtin_amdgcn_mfma_f32_16x16x32_bf16(ahA, bhr1[u], d0b, 0,0,0);
                d1b = __builtin_amdgcn_mfma_f32_16x16x32_bf16(ahB, bhr1[u], d1b, 0,0,0);
            } else {
                d0a = __builtin_amdgcn_mfma_f32_16x16x32_bf16(ahA, bhr1[u], d0a, 0,0,0);
                d1a = __builtin_amdgcn_mfma_f32_16x16x32_bf16(ahB, bhr1[u], d1a, 0,0,0);
            }
        }
        const float4v dA = d0a + d0b;
        const float4v dB = d1a + d1b;
        #pragma unroll
        for (int e = 0; e < 4; ++e){
            const int pp = quad*4 + e;
            atomicAdd(&sLog[pp*LSTR + r2], dA[e]);
            atomicAdd(&sLog[(16+pp)*LSTR + r2], dB[e]);
        }
    }
    __syncthreads();

    // ---- masked softmax (threads 0..511: 16 lanes per pair) ----
    if (t < 512){
        const int pp = t >> 4, l = t & 15;
        const int ri = srp[pp], ci = scp[pp];
        const float* qbk = (const float*)(ws + QBKO);
        float v[4]; float m = NEG_BIG;
        #pragma unroll
        for (int k = 0; k < 4; ++k){
            const int r = l + 16*k;
            float lv = (sLog[pp*LSTR + r] + qbk[b*64 + r]) * SCALE;
            if (r == ri || r == ci) lv = NEG_BIG;
            v[k] = lv; m = fmaxf(m, lv);
        }
        #pragma unroll
        for (int s = 1; s < 16; s <<= 1) m = fmaxf(m, __shfl_xor(m, s));
        float e4[4]; float sum = 0.f;
        #pragma unroll
        for (int k = 0; k < 4; ++k){
            const int r = l + 16*k;
            const bool masked = (r == ri || r == ci);
            const float e = masked ? 0.f : __expf(fmaxf(v[k]-m, -80.f));
            e4[k] = e; sum += e;
        }
        #pragma unroll
        for (int s = 1; s < 16; s <<= 1) sum += __shfl_xor(sum, s);
        const float inv = __builtin_amdgcn_rcpf(sum);
        #pragma unroll
        for (int k = 0; k < 4; ++k) sAl[pp*72 + l + 16*k] = f2b1(e4[k]*inv);
    }
    __syncthreads();

    // ---- phase-4 weight prefetch (independent of sX) ----
    const int mh = w >> 3, nw = w & 7;
    short8 bh4[4];
    #pragma unroll
    for (int ks = 0; ks < 4; ++ks)
        bh4[ks] = *reinterpret_cast<const short8*>(ws + WSH + (nw*16 + l15)*128 + ks*32 + quad*8);

    // ---- phase 3: fused xg + g GEMMs (K=64) + gate, 2 pair-tiles, 2-deep pipeline ----
    {
        const short8 AhA0 = *reinterpret_cast<const short8*>(sAl + l15*72 + quad*8);
        const short8 AhA1 = *reinterpret_cast<const short8*>(sAl + l15*72 + 32 + quad*8);
        const short8 AhB0 = *reinterpret_cast<const short8*>(sAl + (16+l15)*72 + quad*8);
        const short8 AhB1 = *reinterpret_cast<const short8*>(sAl + (16+l15)*72 + 32 + quad*8);
        #pragma unroll
        for (int j = 0; j < 8; ++j){
            const int s = j & 1;
            float4v dxA = {0.f,0.f,0.f,0.f}, dgA = {0.f,0.f,0.f,0.f};
            float4v dxB = {0.f,0.f,0.f,0.f}, dgB = {0.f,0.f,0.f,0.f};
            dxA = __builtin_amdgcn_mfma_f32_16x16x32_bf16(AhA0, px0[s], dxA, 0,0,0);
            dxA = __builtin_amdgcn_mfma_f32_16x16x32_bf16(AhA1, px1[s], dxA, 0,0,0);
            dgA = __builtin_amdgcn_mfma_f32_16x16x32_bf16(AhA0, pg0[s], dgA, 0,0,0);
            dgA = __builtin_amdgcn_mfma_f32_16x16x32_bf16(AhA1, pg1[s], dgA, 0,0,0);
            dxB = __builtin_amdgcn_mfma_f32_16x16x32_bf16(AhB0, px0[s], dxB, 0,0,0);
            dxB = __builtin_amdgcn_mfma_f32_16x16x32_bf16(AhB1, px1[s], dxB, 0,0,0);
            dgB = __builtin_amdgcn_mfma_f32_16x16x32_bf16(AhB0, pg0[s], dgB, 0,0,0);
            dgB = __builtin_amdgcn_mfma_f32_16x16x32_bf16(AhB1, pg1[s], dgB, 0,0,0);
            if (j + 2 < 8){
                const int cd2 = w*128 + (j+2)*16 + l15;
                px0[s] = *reinterpret_cast<const short8*>(XTb + (size_t)cd2*64 + quad*8);
                px1[s] = *reinterpret_cast<const short8*>(XTb + (size_t)cd2*64 + 32 + quad*8);
                pg0[s] = *reinterpret_cast<const short8*>(GTb + (size_t)cd2*64 + quad*8);
                pg1[s] = *reinterpret_cast<const short8*>(GTb + (size_t)cd2*64 + 32 + quad*8);
            }
            const int cd = w*128 + j*16 + l15;
            const int khi = cd >> 7, klo = cd & 127;
            #pragma unroll
            for (int e = 0; e < 4; ++e){
                const int ppA = quad*4 + e;
                const int adA = (ppA*16 + khi)*XSTR + ppA*8 + klo;
                const float wvA = sigmoid_safe(dgA[e]);
                const float xoA = b2f(sX[adA]);
                sX[adA] = f2b1((1.f - wvA)*xoA + wvA*dxA[e]);
                const int ppB = 16 + quad*4 + e;
                const int adB = (ppB*16 + khi)*XSTR + ppB*8 + klo;
                const float wvB = sigmoid_safe(dgB[e]);
                const float xoB = b2f(sX[adB]);
                sX[adB] = f2b1((1.f - wvB)*xoB + wvB*dxB[e]);
            }
        }
    }
    __syncthreads();

    // ---- phase 4: s1-GEMM (M=512) + tanh-gelu + reduce
    // 16 waves = (mh: 2 row-halves) x (nw: 8 n-tiles) ----
    {
        float4v acc16[16];
        const float bv = s1b[nw*16 + l15];
        #pragma unroll
        for (int mt = 0; mt < 16; ++mt){ float4v d = {bv,bv,bv,bv}; acc16[mt] = d; }
        #pragma unroll
        for (int ks = 0; ks < 4; ++ks){
            const int ko = ks*32 + quad*8;
            #pragma unroll
            for (int mt = 0; mt < 16; ++mt){
                const int p = mh*16 + mt;
                const short8 a = *reinterpret_cast<const short8*>(sX + (p*16 + l15)*XSTR + p*8 + ko);
                acc16[mt] = __builtin_amdgcn_mfma_f32_16x16x32_bf16(a, bh4[ks], acc16[mt], 0,0,0);
            }
        }
        const float s2v = s2W[nw*16 + l15];
        const float mk0 = sMask[quad*4+0], mk1 = sMask[quad*4+1];
        const float mk2 = sMask[quad*4+2], mk3 = sMask[quad*4+3];
        float psum[16];
        #pragma unroll
        for (int mt = 0; mt < 16; ++mt){
            float s = gelu_tanh(acc16[mt][0]) * mk0;
            s += gelu_tanh(acc16[mt][1]) * mk1;
            s += gelu_tanh(acc16[mt][2]) * mk2;
            s += gelu_tanh(acc16[mt][3]) * mk3;
            psum[mt] = s * s2v;
        }
        #pragma unroll
        for (int s = 1; s < 64; s <<= 1)
            #pragma unroll
            for (int mt = 0; mt < 16; ++mt) psum[mt] += __shfl_xor(psum[mt], s);
        if (lane == 0){
            #pragma unroll
            for (int mt = 0; mt < 16; ++mt) atomicAdd(&sOut[mh*16 + mt], psum[mt]);
        }
    }
    __syncthreads();

    if (t < PG){
        float msum = 0.f;
        #pragma unroll
        for (int c = 0; c < 16; ++c) msum += sMask[c];
        out[(size_t)b*NPAIR + p0 + t] = sOut[t] + s2b[0]*msum;
    }
}

extern "C" void kernel_launch(void* const* d_in, const int* in_sizes, int n_in,
                              void* d_out, int out_size, void* d_ws, size_t ws_size,
                              hipStream_t stream)
{
    const float* x    = (const float*)d_in[0];
    const float* mask = (const float*)d_in[1];
    const int*   row  = (const int*)d_in[2];
    const int*   col  = (const int*)d_in[3];
    const float* hW  = (const float*)d_in[4];  const float* hb  = (const float*)d_in[5];
    const float* gW  = (const float*)d_in[6];  const float* gb  = (const float*)d_in[7];
    const float* qW  = (const float*)d_in[8];  const float* qb  = (const float*)d_in[9];
    const float* kW  = (const float*)d_in[10]; const float* kb  = (const float*)d_in[11];
    const float* s1W = (const float*)d_in[12]; const float* s1b = (const float*)d_in[13];
    const float* s2W = (const float*)d_in[14]; const float* s2b = (const float*)d_in[15];

    unsigned short* ws = (unsigned short*)d_ws;

    k_prepA<<<65, 256, 0, stream>>>(qW, qb, kW, kb, ws);
    k_prepB<<<260, 512, 0, stream>>>(x, hW, gW, gb, s1W, ws);
    k_main<<<dim3(B_, NPG), 1024, 0, stream>>>(x, mask, row, col,
                                               hb, s1b, s2W, s2b,
                                               ws, (float*)d_out);
}

// Round 8
// 195.149 us; speedup vs baseline: 1.1648x; 1.0078x over previous
//
#include <hip/hip_runtime.h>
#include <hip/hip_bf16.h>
#include <math.h>

#define B_    8
#define R_    64
#define C_    16
#define D_    128
#define NPAIR 2016
#define CD    2048
#define PG    32
#define NPG   63
#define XSTR  136
#define LSTR  68
#define NEG_BIG (-1e30f)
#define SCALE 0.022097086912079608f   // 1/sqrt(2048)

typedef __attribute__((ext_vector_type(8))) short short8;
typedef __attribute__((ext_vector_type(4))) float float4v;

// ---- ws layout (ushort offsets) ----
#define WMH  0u         // P split-hi, layout [d][e]
#define WML  16384u
#define WSH  98304u     // s1W^T plain bf16 [n][k]
#define VECO 131072u    // fp32[257]: mb[0..128), kq[128..256), s0[256]
#define QBKO 131592u    // fp32[512]
#define MO   132616u    // bf16 M[b][r][2048]
#define XTO  1181192u   // bf16 XT[b][cd][64]
#define GTO  2229768u   // bf16 GT[b][cd][64]
#define HO   3278344u   // bf16 H[b][r][2048]

// fast RNE bf16 (inputs finite by construction — no NaN path)
__device__ __forceinline__ unsigned short f2b(float f){
    union { float f; unsigned int u; } v; v.f = f;
    const unsigned int r = v.u + 0x7FFFu + ((v.u >> 16) & 1u);
    return (unsigned short)(r >> 16);
}
__device__ __forceinline__ float b2f(unsigned short u){
    union { unsigned int i; float f; } v; v.i = ((unsigned int)u) << 16; return v.f;
}
__device__ __forceinline__ float lo2f(unsigned int u){
    union { unsigned int i; float f; } v; v.i = u << 16; return v.f;
}
__device__ __forceinline__ float hif2f(unsigned int u){
    union { unsigned int i; float f; } v; v.i = u & 0xffff0000u; return v.f;
}
// single-instruction packed bf16 convert (RNE, same rounding as f2b)
__device__ __forceinline__ unsigned int pack2(float a, float b){
    unsigned int r;
    asm("v_cvt_pk_bf16_f32 %0, %1, %2" : "=v"(r) : "v"(a), "v"(b));
    return r;
}
__device__ __forceinline__ unsigned short f2b1(float a){
    unsigned int r;
    asm("v_cvt_pk_bf16_f32 %0, %1, %1" : "=v"(r) : "v"(a));
    return (unsigned short)r;
}
__device__ __forceinline__ void split_bf(float v, float* hi, float* lo){
    union { float f; unsigned int u; } x; x.f = v;
    const unsigned int r = (x.u + 0x7FFFu + ((x.u >> 16) & 1u)) & 0xffff0000u;
    union { unsigned int u; float f; } h; h.u = r;
    *hi = h.f; *lo = v - h.f;
}
// split to bf16 pair directly (bit-identical to split_bf + f2b on both halves)
__device__ __forceinline__ void splitw(float v, short* h, short* l){
    union { float f; unsigned int u; } x; x.f = v;
    const unsigned int rh = (x.u + 0x7FFFu + ((x.u >> 16) & 1u)) & 0xffff0000u;
    union { unsigned int u; float f; } hf; hf.u = rh;
    *h = (short)(rh >> 16);
    *l = (short)f2b(v - hf.f);
}
// no clamp needed: exp(+inf)->inf, rcp(inf)->0 ; exp(-inf)->0 -> 1. Inputs finite.
__device__ __forceinline__ float sigmoid_safe(float x){
    return __builtin_amdgcn_rcpf(1.f + __expf(-x));
}
// tanh-GELU via sigmoid identity (empirically error-neutral here, R12/R13 data)
__device__ __forceinline__ float gelu_tanh(float x){
    const float u = x*x;
    const float g2 = x*(1.5957691216057308f + 0.07135481627159f*u);
    return x * sigmoid_safe(g2);
}

// ===== launch A (small): P split + vectors only (65 blocks) =====
__global__ __launch_bounds__(256) void k_prepA(
    const float* __restrict__ qW, const float* __restrict__ qb,
    const float* __restrict__ kW, const float* __restrict__ kb,
    unsigned short* __restrict__ ws)
{
    const int bid = blockIdx.x, t = threadIdx.x;
    if (bid < 64){
        __shared__ float sKW[2][128];
        const int e0 = bid*2;
        sKW[t>>7][t&127] = kW[(e0 + (t>>7))*128 + (t&127)];
        __syncthreads();
        const int e = t>>7, d = t&127;
        const float* qr = qW + d*128;
        const float* kr = sKW[e];
        float acc = 0.f;
        #pragma unroll 8
        for (int g = 0; g < 128; g += 4){
            const float4 qv = *reinterpret_cast<const float4*>(qr + g);
            acc += qv.x*kr[g] + qv.y*kr[g+1] + qv.z*kr[g+2] + qv.w*kr[g+3];
        }
        float hi, lo; split_bf(acc, &hi, &lo);
        ws[WMH + d*128 + (e0+e)] = f2b(hi);
        ws[WML + d*128 + (e0+e)] = f2b(lo);
    } else {
        float* vec = (float*)(ws + VECO);
        if (t < 128){
            float a1 = 0.f, a2 = 0.f;
            #pragma unroll 8
            for (int g = 0; g < 128; g += 4){
                const float4 q4 = *reinterpret_cast<const float4*>(qW + t*128 + g);
                const float4 k4 = *reinterpret_cast<const float4*>(kW + t*128 + g);
                const float4 kb4 = *reinterpret_cast<const float4*>(kb + g);
                const float4 qb4 = *reinterpret_cast<const float4*>(qb + g);
                a1 += q4.x*kb4.x + q4.y*kb4.y + q4.z*kb4.z + q4.w*kb4.w;
                a2 += k4.x*qb4.x + k4.y*qb4.y + k4.z*qb4.z + k4.w*qb4.w;
            }
            vec[t] = a1;        // mb[d]
            vec[128 + t] = a2;  // kq[e]
        } else if (t == 128){
            float a = 0.f;
            for (int g = 0; g < 128; ++g) a = fmaf(qb[g], kb[g], a);
            vec[256] = a;       // s0
        }
    }
}

// ===== launch B (fused): [0,128) H+M | [128,256) GT+XT | [256,260) s1W cvt =====
__global__ __launch_bounds__(512) void k_prepB(const float* __restrict__ x,
        const float* __restrict__ hW, const float* __restrict__ gW,
        const float* __restrict__ gb, const float* __restrict__ s1W,
        unsigned short* __restrict__ ws)
{
    __shared__ __align__(16) unsigned short smem[8832];
    __shared__ float sQ[4];
    const int bid = blockIdx.x, t = threadIdx.x;
    const int w = t >> 6, lane = t & 63, l15 = lane & 15, quad = lane >> 4;

    if (bid < 128){
        // ---- fused H + M for rows br0..br0+3 ----
        unsigned short* sH = smem;
        const int br0 = bid * 4;
        const float* kqf = (const float*)(ws + VECO) + 128;
        const float* mbf = (const float*)(ws + VECO);
        if (t < 4) sQ[t] = 0.f;
        __syncthreads();
        float qacc[4] = {0.f, 0.f, 0.f, 0.f};
        #pragma unroll
        for (int i = 0; i < 4; ++i){
            const int flat = (t + 512*i)*4;
            const int lr = i;
            const int cd = flat & 2047;
            const float4 v = *reinterpret_cast<const float4*>(x + (size_t)(br0+lr)*CD + cd);
            const int ad = (lr*16 + (cd>>7))*XSTR + lr*8 + (cd & 127);
            uint2 uh;
            uh.x = pack2(v.x, v.y); uh.y = pack2(v.z, v.w);
            *reinterpret_cast<uint2*>(sH + ad) = uh;
            const float4 kq4 = *reinterpret_cast<const float4*>(kqf + (cd & 127));
            qacc[i] = v.x*kq4.x + v.y*kq4.y + v.z*kq4.z + v.w*kq4.w;
        }
        #pragma unroll
        for (int i = 0; i < 4; ++i){
            float s = qacc[i];
            #pragma unroll
            for (int off = 1; off < 64; off <<= 1) s += __shfl_xor(s, off);
            if (lane == 0) atomicAdd(&sQ[i], s);
        }
        __syncthreads();
        // --- M pass (P tables) ---
        {
            const float bv = mbf[w*16 + l15];
            float4v acc[4];
            #pragma unroll
            for (int mt = 0; mt < 4; ++mt){ float4v d = {bv,bv,bv,bv}; acc[mt] = d; }
            #pragma unroll
            for (int ks = 0; ks < 4; ++ks){
                const int ko = ks*32 + quad*8;
                const int bd = (w*16 + l15)*128 + ko;
                const short8 bh = *reinterpret_cast<const short8*>(ws + WMH + bd);
                const short8 bl = *reinterpret_cast<const short8*>(ws + WML + bd);
                #pragma unroll
                for (int mt = 0; mt < 4; ++mt){
                    const int ad = (mt*16 + l15)*XSTR + mt*8 + ko;
                    const short8 ah = *reinterpret_cast<const short8*>(sH + ad);
                    float4v d = acc[mt];
                    d = __builtin_amdgcn_mfma_f32_16x16x32_bf16(ah, bh, d, 0,0,0);
                    d = __builtin_amdgcn_mfma_f32_16x16x32_bf16(ah, bl, d, 0,0,0);
                    acc[mt] = d;
                }
            }
            const int f = w*16 + l15;
            #pragma unroll
            for (int mt = 0; mt < 4; ++mt)
            #pragma unroll
            for (int e = 0; e < 4; ++e){
                const int c = quad*4 + e;
                ws[MO + (size_t)(br0+mt)*CD + c*128 + f] = f2b(acc[mt][e]);
            }
            if (t < 4){
                const float s0 = ((const float*)(ws + VECO))[256];
                ((float*)(ws + QBKO))[br0 + t] = sQ[t] + 16.f*s0;
            }
        }
        // --- H pass (on-the-fly hW split) ---
        {
            const int n = w*16 + l15;
            float4v acc[4];
            #pragma unroll
            for (int mt = 0; mt < 4; ++mt){ float4v z = {0.f,0.f,0.f,0.f}; acc[mt] = z; }
            #pragma unroll
            for (int ks = 0; ks < 4; ++ks){
                const int ko = ks*32 + quad*8;
                short8 bh, bl;
                #pragma unroll
                for (int j = 0; j < 8; ++j){
                    short hh, ll;
                    splitw(hW[(size_t)(ko+j)*128 + n], &hh, &ll);
                    bh[j] = hh; bl[j] = ll;
                }
                #pragma unroll
                for (int mt = 0; mt < 4; ++mt){
                    const int ad = (mt*16 + l15)*XSTR + mt*8 + ko;
                    const short8 ah = *reinterpret_cast<const short8*>(sH + ad);
                    float4v d = acc[mt];
                    d = __builtin_amdgcn_mfma_f32_16x16x32_bf16(ah, bh, d, 0,0,0);
                    d = __builtin_amdgcn_mfma_f32_16x16x32_bf16(ah, bl, d, 0,0,0);
                    acc[mt] = d;
                }
            }
            #pragma unroll
            for (int mt = 0; mt < 4; ++mt)
            #pragma unroll
            for (int e = 0; e < 4; ++e){
                const int c = quad*4 + e;
                ws[HO + (size_t)(br0+mt)*CD + c*128 + n] = f2b(acc[mt][e]);
            }
        }
    } else if (bid < 256){
        // ---- fused GT + XT for (b, cd0) tile ----
        unsigned short* tileB = smem;   // [r][d] stride 138
        const int gidx = bid - 128;
        const int b = gidx >> 4, cd0 = (gidx & 15)*128;
        #pragma unroll
        for (int i = 0; i < 16; ++i){
            const int idx = i*512 + t;
            const int r = idx >> 7, dd = idx & 127;
            tileB[r*138 + dd] = f2b(x[(size_t)(b*64 + r)*CD + cd0 + dd]);
        }
        __syncthreads();
        // XT = transpose of tileB (coalesced global writes)
        {
            const unsigned int base = XTO + (unsigned int)(b*2048 + cd0)*64;
            #pragma unroll
            for (int j = 0; j < 16; ++j){
                const int idx = j*512 + t;
                const int cc = idx >> 6, r = idx & 63;
                ws[base + cc*64 + r] = tileB[r*138 + cc];
            }
        }
        // GT MFMA (on-the-fly gW split)
        const int fA = w*16 + l15;
        float4v acc[4];
        #pragma unroll
        for (int nt = 0; nt < 4; ++nt){ float4v z = {0.f,0.f,0.f,0.f}; acc[nt] = z; }
        #pragma unroll
        for (int ks = 0; ks < 4; ++ks){
            const int ko = ks*32 + quad*8;
            short8 ah, al;
            #pragma unroll
            for (int j = 0; j < 8; ++j){
                short hh, ll;
                splitw(gW[(size_t)(ko+j)*128 + fA], &hh, &ll);
                ah[j] = hh; al[j] = ll;
            }
            #pragma unroll
            for (int nt = 0; nt < 4; ++nt){
                const short8 bb = *reinterpret_cast<const short8*>(tileB + (nt*16 + l15)*138 + ko);
                float4v d = acc[nt];
                d = __builtin_amdgcn_mfma_f32_16x16x32_bf16(ah, bb, d, 0,0,0);
                d = __builtin_amdgcn_mfma_f32_16x16x32_bf16(al, bb, d, 0,0,0);
                acc[nt] = d;
            }
        }
        #pragma unroll
        for (int nt = 0; nt < 4; ++nt)
        #pragma unroll
        for (int e = 0; e < 4; ++e){
            const int f = w*16 + quad*4 + e;
            const float val = acc[nt][e] + gb[f];
            ws[GTO + (size_t)(b*2048 + cd0 + f)*64 + nt*16 + l15] = f2b(val);
        }
    } else {
        // s1W^T plain bf16 convert
        const int gid = (bid - 256)*4096 + t;
        #pragma unroll
        for (int i = 0; i < 8; ++i){
            const int g = gid + i*512;
            const int n = g >> 7, k = g & 127;
            ws[WSH + g] = f2b(s1W[k*128 + n]);
        }
    }
}

// =========== main fused kernel: grid (b, 63), 1024 threads, PG=32 ===========
// 1 block/CU. Cross-phase register prefetch (R7). Phase 3 computes the
// TRANSPOSED tile via swapped MFMA operands (A/B frag layouts are symmetric)
// so each lane's 4 outputs are 4 consecutive cd of ONE pair -> gate does
// ds_read_b64/ds_write_b64 instead of 8 scattered u16 RMWs per tile.
__global__ __launch_bounds__(1024, 4) void k_main(
    const float* __restrict__ x, const float* __restrict__ seq_mask,
    const int* __restrict__ row, const int* __restrict__ col,
    const float* __restrict__ hb, const float* __restrict__ s1b,
    const float* __restrict__ s2W, const float* __restrict__ s2b,
    const unsigned short* __restrict__ ws, float* __restrict__ out)
{
    __shared__ __align__(16) unsigned short sX[512*XSTR + 256];
    __shared__ __align__(16) unsigned short sAl[32*72];
    __shared__ float sLog[32*LSTR];
    __shared__ float sOut[PG];
    __shared__ float sMask[16];
    __shared__ int srp[PG], scp[PG];

    const int t = threadIdx.x;
    const int w = t >> 6, lane = t & 63, l15 = lane & 15, quad = lane >> 4;
    const int b = blockIdx.x, p0 = blockIdx.y * PG;
    const float* xb = x + (size_t)b * R_ * CD;
    const unsigned short* Hb = ws + HO + (size_t)b * R_ * CD;

    // ---- phase-2 B-panel prefetch, half 0 (independent of phase 1) ----
    const int rt = w & 3, kh = w >> 2;
    const int r2 = rt*16 + l15;
    const unsigned short* Mr = ws + MO + ((size_t)b*64 + r2)*CD + kh*512;
    short8 bhr0[8];
    #pragma unroll
    for (int u = 0; u < 8; ++u)
        bhr0[u] = *reinterpret_cast<const short8*>(Mr + u*32 + quad*8);

    if (t < PG){ srp[t] = row[p0+t]; scp[t] = col[p0+t]; sOut[t] = 0.f; }
    if (t >= 32 && t < 48) sMask[t-32] = seq_mask[b*C_ + (t-32)];
    for (int i = t; i < 32*LSTR; i += 1024) sLog[i] = 0.f;
    __syncthreads();

    // ---- phase 1: fused stage + h-gate, 8 elem/iter ----
    #pragma unroll
    for (int i = 0; i < 8; ++i){
        const int flat = (t + 1024*i)*8;
        const int p = flat >> 11, cd = flat & 2047;
        const int ri = srp[p], ci = scp[p];
        const float* xip = xb + (size_t)ri*CD + cd;
        const float* xjp = xb + (size_t)ci*CD + cd;
        const float4 xi0 = *reinterpret_cast<const float4*>(xip);
        const float4 xi1 = *reinterpret_cast<const float4*>(xip + 4);
        const float4 xj0 = *reinterpret_cast<const float4*>(xjp);
        const float4 xj1 = *reinterpret_cast<const float4*>(xjp + 4);
        const uint4 Hi4 = *reinterpret_cast<const uint4*>(Hb + (size_t)ri*CD + cd);
        const uint4 Hj4 = *reinterpret_cast<const uint4*>(Hb + (size_t)ci*CD + cd);
        const float4 h40 = *reinterpret_cast<const float4*>(hb + (cd & 127));
        const float4 h41 = *reinterpret_cast<const float4*>(hb + (cd & 127) + 4);
        const float z0 = sigmoid_safe(lo2f(Hi4.x)  - lo2f(Hj4.x)  + h40.x);
        const float z1 = sigmoid_safe(hif2f(Hi4.x) - hif2f(Hj4.x) + h40.y);
        const float z2 = sigmoid_safe(lo2f(Hi4.y)  - lo2f(Hj4.y)  + h40.z);
        const float z3 = sigmoid_safe(hif2f(Hi4.y) - hif2f(Hj4.y) + h40.w);
        const float z4 = sigmoid_safe(lo2f(Hi4.z)  - lo2f(Hj4.z)  + h41.x);
        const float z5 = sigmoid_safe(hif2f(Hi4.z) - hif2f(Hj4.z) + h41.y);
        const float z6 = sigmoid_safe(lo2f(Hi4.w)  - lo2f(Hj4.w)  + h41.z);
        const float z7 = sigmoid_safe(hif2f(Hi4.w) - hif2f(Hj4.w) + h41.w);
        const float v0 = xj0.x + z0*(xi0.x - xj0.x);
        const float v1 = xj0.y + z1*(xi0.y - xj0.y);
        const float v2 = xj0.z + z2*(xi0.z - xj0.z);
        const float v3 = xj0.w + z3*(xi0.w - xj0.w);
        const float v4 = xj1.x + z4*(xi1.x - xj1.x);
        const float v5 = xj1.y + z5*(xi1.y - xj1.y);
        const float v6 = xj1.z + z6*(xi1.z - xj1.z);
        const float v7 = xj1.w + z7*(xi1.w - xj1.w);
        const int ad = (p*16 + (cd>>7))*XSTR + p*8 + (cd & 127);
        uint4 uv;
        uv.x = pack2(v0,v1); uv.y = pack2(v2,v3);
        uv.z = pack2(v4,v5); uv.w = pack2(v6,v7);
        *reinterpret_cast<uint4*>(sX + ad) = uv;
    }
    __syncthreads();

    // ---- phase 3 stream pointers (prefetch issued mid-phase-2) ----
    const unsigned short* XTb = ws + XTO + (size_t)b * CD * 64;
    const unsigned short* GTb = ws + GTO + (size_t)b * CD * 64;
    short8 px0[2], px1[2], pg0[2], pg1[2];

    // ---- phase 2: alpha GEMM logits[p][r] = x . M[b,r] ----
    {
        // issue half-1 B loads first
        short8 bhr1[8];
        #pragma unroll
        for (int u = 0; u < 8; ++u)
            bhr1[u] = *reinterpret_cast<const short8*>(Mr + (8+u)*32 + quad*8);
        float4v d0a = {0.f,0.f,0.f,0.f}, d0b = {0.f,0.f,0.f,0.f};
        float4v d1a = {0.f,0.f,0.f,0.f}, d1b = {0.f,0.f,0.f,0.f};
        #pragma unroll
        for (int u = 0; u < 8; ++u){
            const int k = kh*512 + u*32 + quad*8;
            const int khi = k >> 7, klo = k & 127;
            const short8 ahA = *reinterpret_cast<const short8*>(
                sX + (l15*16 + khi)*XSTR + l15*8 + klo);
            const short8 ahB = *reinterpret_cast<const short8*>(
                sX + ((16+l15)*16 + khi)*XSTR + (16+l15)*8 + klo);
            if (u & 1){
                d0b = __builtin_amdgcn_mfma_f32_16x16x32_bf16(ahA, bhr0[u], d0b, 0,0,0);
                d1b = __builtin_amdgcn_mfma_f32_16x16x32_bf16(ahB, bhr0[u], d1b, 0,0,0);
            } else {
                d0a = __builtin_amdgcn_mfma_f32_16x16x32_bf16(ahA, bhr0[u], d0a, 0,0,0);
                d1a = __builtin_amdgcn_mfma_f32_16x16x32_bf16(ahB, bhr0[u], d1a, 0,0,0);
            }
        }
        // phase-3 prefetch: overlaps half-1 MFMAs + barrier + softmax
        #pragma unroll
        for (int j = 0; j < 2; ++j){
            const int cd = w*128 + j*16 + l15;
            px0[j] = *reinterpret_cast<const short8*>(XTb + (size_t)cd*64 + quad*8);
            px1[j] = *reinterpret_cast<const short8*>(XTb + (size_t)cd*64 + 32 + quad*8);
            pg0[j] = *reinterpret_cast<const short8*>(GTb + (size_t)cd*64 + quad*8);
            pg1[j] = *reinterpret_cast<const short8*>(GTb + (size_t)cd*64 + 32 + quad*8);
        }
        #pragma unroll
        for (int u = 0; u < 8; ++u){
            const int k = kh*512 + (8+u)*32 + quad*8;
            const int khi = k >> 7, klo = k & 127;
            const short8 ahA = *reinterpret_cast<const short8*>(
                sX + (l15*16 + khi)*XSTR + l15*8 + klo);
            const short8 ahB = *reinterpret_cast<const short8*>(
                sX + ((16+l15)*16 + khi)*XSTR + (16+l15)*8 + klo);
            if (u & 1){
                d0b = __builtin_amdgcn_mfma_f32_16x16x32_bf16(ahA, bhr1[u], d0b, 0,0,0);
                d1b = __builtin_amdgcn_mfma_f32_16x16x32_bf16(ahB, bhr1[u], d1b, 0,0,0);
            } else {
                d0a = __builtin_amdgcn_mfma_f32_16x16x32_bf16(ahA, bhr1[u], d0a, 0,0,0);
                d1a = __builtin_amdgcn_mfma_f32_16x16x32_bf16(ahB, bhr1[u], d1a, 0,0,0);
            }
        }
        const float4v dA = d0a + d0b;
        const float4v dB = d1a + d1b;
        #pragma unroll
        for (int e = 0; e < 4; ++e){
            const int pp = quad*4 + e;
            atomicAdd(&sLog[pp*LSTR + r2], dA[e]);
            atomicAdd(&sLog[(16+pp)*LSTR + r2], dB[e]);
        }
    }
    __syncthreads();

    // ---- masked softmax (threads 0..511: 16 lanes per pair) ----
    if (t < 512){
        const int pp = t >> 4, l = t & 15;
        const int ri = srp[pp], ci = scp[pp];
        const float* qbk = (const float*)(ws + QBKO);
        float v[4]; float m = NEG_BIG;
        #pragma unroll
        for (int k = 0; k < 4; ++k){
            const int r = l + 16*k;
            float lv = (sLog[pp*LSTR + r] + qbk[b*64 + r]) * SCALE;
            if (r == ri || r == ci) lv = NEG_BIG;
            v[k] = lv; m = fmaxf(m, lv);
        }
        #pragma unroll
        for (int s = 1; s < 16; s <<= 1) m = fmaxf(m, __shfl_xor(m, s));
        float e4[4]; float sum = 0.f;
        #pragma unroll
        for (int k = 0; k < 4; ++k){
            const int r = l + 16*k;
            const bool masked = (r == ri || r == ci);
            const float e = masked ? 0.f : __expf(fmaxf(v[k]-m, -80.f));
            e4[k] = e; sum += e;
        }
        #pragma unroll
        for (int s = 1; s < 16; s <<= 1) sum += __shfl_xor(sum, s);
        const float inv = __builtin_amdgcn_rcpf(sum);
        #pragma unroll
        for (int k = 0; k < 4; ++k) sAl[pp*72 + l + 16*k] = f2b1(e4[k]*inv);
    }
    __syncthreads();

    // ---- phase-4 weight prefetch (independent of sX) ----
    const int mh = w >> 3, nw = w & 7;
    short8 bh4[4];
    #pragma unroll
    for (int ks = 0; ks < 4; ++ks)
        bh4[ks] = *reinterpret_cast<const short8*>(ws + WSH + (nw*16 + l15)*128 + ks*32 + quad*8);

    // ---- phase 3: fused xg + g GEMMs (K=64) + gate, TRANSPOSED tiles ----
    // mfma(px, Ah) -> D[cd_local][pair]: lane's 4 elems = 4 consecutive cd of
    // pair l15 (half A) / 16+l15 (half B) -> b64 LDS RMW.
    {
        const short8 AhA0 = *reinterpret_cast<const short8*>(sAl + l15*72 + quad*8);
        const short8 AhA1 = *reinterpret_cast<const short8*>(sAl + l15*72 + 32 + quad*8);
        const short8 AhB0 = *reinterpret_cast<const short8*>(sAl + (16+l15)*72 + quad*8);
        const short8 AhB1 = *reinterpret_cast<const short8*>(sAl + (16+l15)*72 + 32 + quad*8);
        #pragma unroll
        for (int j = 0; j < 8; ++j){
            const int s = j & 1;
            float4v dxA = {0.f,0.f,0.f,0.f}, dgA = {0.f,0.f,0.f,0.f};
            float4v dxB = {0.f,0.f,0.f,0.f}, dgB = {0.f,0.f,0.f,0.f};
            dxA = __builtin_amdgcn_mfma_f32_16x16x32_bf16(px0[s], AhA0, dxA, 0,0,0);
            dxA = __builtin_amdgcn_mfma_f32_16x16x32_bf16(px1[s], AhA1, dxA, 0,0,0);
            dgA = __builtin_amdgcn_mfma_f32_16x16x32_bf16(pg0[s], AhA0, dgA, 0,0,0);
            dgA = __builtin_amdgcn_mfma_f32_16x16x32_bf16(pg1[s], AhA1, dgA, 0,0,0);
            dxB = __builtin_amdgcn_mfma_f32_16x16x32_bf16(px0[s], AhB0, dxB, 0,0,0);
            dxB = __builtin_amdgcn_mfma_f32_16x16x32_bf16(px1[s], AhB1, dxB, 0,0,0);
            dgB = __builtin_amdgcn_mfma_f32_16x16x32_bf16(pg0[s], AhB0, dgB, 0,0,0);
            dgB = __builtin_amdgcn_mfma_f32_16x16x32_bf16(pg1[s], AhB1, dgB, 0,0,0);
            if (j + 2 < 8){
                const int cd2 = w*128 + (j+2)*16 + l15;
                px0[s] = *reinterpret_cast<const short8*>(XTb + (size_t)cd2*64 + quad*8);
                px1[s] = *reinterpret_cast<const short8*>(XTb + (size_t)cd2*64 + 32 + quad*8);
                pg0[s] = *reinterpret_cast<const short8*>(GTb + (size_t)cd2*64 + quad*8);
                pg1[s] = *reinterpret_cast<const short8*>(GTb + (size_t)cd2*64 + 32 + quad*8);
            }
            const int klo = j*16 + quad*4;     // 4 consecutive cd, all < 128
            // half A: pair = l15
            {
                const int ad = (l15*16 + w)*XSTR + l15*8 + klo;
                uint2 xo = *reinterpret_cast<const uint2*>(sX + ad);
                const float o0 = lo2f(xo.x), o1 = hif2f(xo.x);
                const float o2 = lo2f(xo.y), o3 = hif2f(xo.y);
                const float w0 = sigmoid_safe(dgA[0]);
                const float w1 = sigmoid_safe(dgA[1]);
                const float w2 = sigmoid_safe(dgA[2]);
                const float w3 = sigmoid_safe(dgA[3]);
                const float n0 = (1.f - w0)*o0 + w0*dxA[0];
                const float n1 = (1.f - w1)*o1 + w1*dxA[1];
                const float n2 = (1.f - w2)*o2 + w2*dxA[2];
                const float n3 = (1.f - w3)*o3 + w3*dxA[3];
                uint2 nv; nv.x = pack2(n0, n1); nv.y = pack2(n2, n3);
                *reinterpret_cast<uint2*>(sX + ad) = nv;
            }
            // half B: pair = 16 + l15
            {
                const int ad = ((16+l15)*16 + w)*XSTR + (16+l15)*8 + klo;
                uint2 xo = *reinterpret_cast<const uint2*>(sX + ad);
                const float o0 = lo2f(xo.x), o1 = hif2f(xo.x);
                const float o2 = lo2f(xo.y), o3 = hif2f(xo.y);
                const float w0 = sigmoid_safe(dgB[0]);
                const float w1 = sigmoid_safe(dgB[1]);
                const float w2 = sigmoid_safe(dgB[2]);
                const float w3 = sigmoid_safe(dgB[3]);
                const float n0 = (1.f - w0)*o0 + w0*dxB[0];
                const float n1 = (1.f - w1)*o1 + w1*dxB[1];
                const float n2 = (1.f - w2)*o2 + w2*dxB[2];
                const float n3 = (1.f - w3)*o3 + w3*dxB[3];
                uint2 nv; nv.x = pack2(n0, n1); nv.y = pack2(n2, n3);
                *reinterpret_cast<uint2*>(sX + ad) = nv;
            }
        }
    }
    __syncthreads();

    // ---- phase 4: s1-GEMM (M=512) + tanh-gelu + reduce
    // 16 waves = (mh: 2 row-halves) x (nw: 8 n-tiles) ----
    {
        float4v acc16[16];
        const float bv = s1b[nw*16 + l15];
        #pragma unroll
        for (int mt = 0; mt < 16; ++mt){ float4v d = {bv,bv,bv,bv}; acc16[mt] = d; }
        #pragma unroll
        for (int ks = 0; ks < 4; ++ks){
            const int ko = ks*32 + quad*8;
            #pragma unroll
            for (int mt = 0; mt < 16; ++mt){
                const int p = mh*16 + mt;
                const short8 a = *reinterpret_cast<const short8*>(sX + (p*16 + l15)*XSTR + p*8 + ko);
                acc16[mt] = __builtin_amdgcn_mfma_f32_16x16x32_bf16(a, bh4[ks], acc16[mt], 0,0,0);
            }
        }
        const float s2v = s2W[nw*16 + l15];
        const float mk0 = sMask[quad*4+0], mk1 = sMask[quad*4+1];
        const float mk2 = sMask[quad*4+2], mk3 = sMask[quad*4+3];
        float psum[16];
        #pragma unroll
        for (int mt = 0; mt < 16; ++mt){
            float s = gelu_tanh(acc16[mt][0]) * mk0;
            s += gelu_tanh(acc16[mt][1]) * mk1;
            s += gelu_tanh(acc16[mt][2]) * mk2;
            s += gelu_tanh(acc16[mt][3]) * mk3;
            psum[mt] = s * s2v;
        }
        #pragma unroll
        for (int s = 1; s < 64; s <<= 1)
            #pragma unroll
            for (int mt = 0; mt < 16; ++mt) psum[mt] += __shfl_xor(psum[mt], s);
        if (lane == 0){
            #pragma unroll
            for (int mt = 0; mt < 16; ++mt) atomicAdd(&sOut[mh*16 + mt], psum[mt]);
        }
    }
    __syncthreads();

    if (t < PG){
        float msum = 0.f;
        #pragma unroll
        for (int c = 0; c < 16; ++c) msum += sMask[c];
        out[(size_t)b*NPAIR + p0 + t] = sOut[t] + s2b[0]*msum;
    }
}

extern "C" void kernel_launch(void* const* d_in, const int* in_sizes, int n_in,
                              void* d_out, int out_size, void* d_ws, size_t ws_size,
                              hipStream_t stream)
{
    const float* x    = (const float*)d_in[0];
    const float* mask = (const float*)d_in[1];
    const int*   row  = (const int*)d_in[2];
    const int*   col  = (const int*)d_in[3];
    const float* hW  = (const float*)d_in[4];  const float* hb  = (const float*)d_in[5];
    const float* gW  = (const float*)d_in[6];  const float* gb  = (const float*)d_in[7];
    const float* qW  = (const float*)d_in[8];  const float* qb  = (const float*)d_in[9];
    const float* kW  = (const float*)d_in[10]; const float* kb  = (const float*)d_in[11];
    const float* s1W = (const float*)d_in[12]; const float* s1b = (const float*)d_in[13];
    const float* s2W = (const float*)d_in[14]; const float* s2b = (const float*)d_in[15];

    unsigned short* ws = (unsigned short*)d_ws;

    k_prepA<<<65, 256, 0, stream>>>(qW, qb, kW, kb, ws);
    k_prepB<<<260, 512, 0, stream>>>(x, hW, gW, gb, s1W, ws);
    k_main<<<dim3(B_, NPG), 1024, 0, stream>>>(x, mask, row, col,
                                               hb, s1b, s2W, s2b,
                                               ws, (float*)d_out);
}